// Round 1
// baseline (238.385 us; speedup 1.0000x reference)
//
#include <hip/hip_runtime.h>
#include <hip/hip_cooperative_groups.h>
#include <cstdint>
#include <cstddef>

namespace cg = cooperative_groups;

typedef int   v4i __attribute__((ext_vector_type(4)));
typedef float v4f __attribute__((ext_vector_type(4)));

static constexpr int NREP = 8;    // stats replica count (atomic contention spreading)

// ---------------- workspace layout (bytes) ----------------
static constexpr size_t WQ_OFF    = 0;                        // 65536 int8 weights
static constexpr size_t STATS_OFF = 65536;                    // NREP*512 int32 = 16384
static constexpr size_t PART_OFF  = STATS_OFF + NREP*512*4;   // 64 floats
static constexpr size_t SBUF_OFF  = 131072 + 2048;            // 16 MiB s-values (fallback path)
static constexpr size_t WS_SBUF_NEEDED = SBUF_OFF + (size_t)65536 * 256;
static constexpr size_t WS_MIN    = PART_OFF + 64 * 4;        // cooperative path needs only this

// exact round-half-even of p/1792 for |p| <= 13440 (1792 = 7*256)
__device__ __forceinline__ int rhe1792(int p) {
    unsigned u = (unsigned)(p + 17024);      // (p+896) + 9*1792, u in [3584,30464]
    unsigned v = u >> 8;                     // floor(u/256), in [14,119]
    unsigned d = (v * 147u) >> 10;           // floor(v/7), exact for v<=119
    int q = (int)d - 9;                      // round-half-up(p/1792)
    unsigned tie = (unsigned)(((u & 255u) | (v - 7u * d)) == 0u);
    q -= (int)(tie & ((unsigned)q & 1u));    // half-even: ties round to even
    return q;
}

// ---------------- k1: per-block max|w| partials + zero stats ----------------
__global__ void k_maxabs(const float* __restrict__ w, float* __restrict__ partials,
                         int* __restrict__ stats) {
    __shared__ float wmax[4];
    int idx = blockIdx.x * 256 + threadIdx.x;     // 64 blocks * 256 = 16384 float4
    float4 f = ((const float4*)w)[idx];
    float m = fmaxf(fmaxf(fabsf(f.x), fabsf(f.y)), fmaxf(fabsf(f.z), fabsf(f.w)));
    #pragma unroll
    for (int s = 32; s > 0; s >>= 1) m = fmaxf(m, __shfl_xor(m, s, 64));
    if ((threadIdx.x & 63) == 0) wmax[threadIdx.x >> 6] = m;
    if (idx < NREP * 512) stats[idx] = 0;         // zero replicas
    __syncthreads();
    if (threadIdx.x == 0)
        partials[blockIdx.x] = fmaxf(fmaxf(wmax[0], wmax[1]), fmaxf(wmax[2], wmax[3]));
}

// wave-redundant reduce of the 64 partials (L2-hot) -> global max|w|
__device__ __forceinline__ float reduce_partials(const float* __restrict__ partials, int tid) {
    float p = partials[tid & 63];
    #pragma unroll
    for (int s = 32; s > 0; s >>= 1) p = fmaxf(p, __shfl_xor(p, s, 64));
    return p;
}

// ---------------- k2: quantize weights to int8 ----------------
__global__ void k_wquant(const float* __restrict__ w, const float* __restrict__ partials,
                         signed char* __restrict__ wq) {
    int idx = blockIdx.x * 256 + threadIdx.x;
    float scale = reduce_partials(partials, threadIdx.x) / 7.0f;  // scale_w (f32 div, as ref)
    float4 f = ((const float4*)w)[idx];
    int q0 = (int)rintf(fminf(fmaxf(f.x / scale, -7.f), 7.f));
    int q1 = (int)rintf(fminf(fmaxf(f.y / scale, -7.f), 7.f));
    int q2 = (int)rintf(fminf(fmaxf(f.z / scale, -7.f), 7.f));
    int q3 = (int)rintf(fminf(fmaxf(f.w / scale, -7.f), 7.f));
    ((int*)wq)[idx] = (q0 & 255) | ((q1 & 255) << 8) | ((q2 & 255) << 16) | ((q3 & 255) << 24);
}

// ---------------- k3 (cooperative): GEMM + stats, grid.sync, BN + output ----
// 512 blocks x 512 threads, 128 batch rows/block, s held IN REGISTERS across
// the grid sync (no sbuf round-trip). MFMA operands SWAPPED vs the old k_gemm
// (A = weights, B = acts): C-fragment row = channel (quad*4+e, 4 consecutive),
// col = batch row (lr) -> phase-2 writes are float4 per thread, 64B clusters.
// __launch_bounds__(512,4) caps VGPR at 128 -> exactly 2 blocks/CU, 512
// co-resident blocks (validated by hipLaunchCooperativeKernel).
__global__ __launch_bounds__(512, 4) void k_fused(
    const float* __restrict__ x, const signed char* __restrict__ wq,
    const float* __restrict__ partials, int* __restrict__ stats,
    const float* __restrict__ gamma, const float* __restrict__ beta,
    float* __restrict__ out)
{
    __shared__ __align__(16) signed char ldsx[128 * 272];  // 128 rows x 256 k (+16B pad/row)
    __shared__ __align__(16) float abA[256];
    __shared__ __align__(16) float abB[256];

    const int tid  = threadIdx.x;
    const int lane = tid & 63;
    const int wv   = tid >> 6;            // 0..7
    const int obase = wv * 32;            // 32 channels per wave
    const int lr = lane & 15, quad = lane >> 4;
    const size_t rb0 = (size_t)blockIdx.x * 128;

    // ---- x loads rows 0..63 (coalesced 8KB/inst) ----
    v4f f[8];
    const v4f* xb = (const v4f*)(x + rb0 * 256);
    #pragma unroll
    for (int j = 0; j < 8; ++j)
        f[j] = xb[j * 512 + tid];

    // ---- weight fragments (L2-hot), same bytes as old B-fragments, used as A:
    //      A row r = lane&15 -> channel obase+ot*16+lr, k = kt*64 + quad*16 + i ----
    v4i wf[2][4];
    #pragma unroll
    for (int ot = 0; ot < 2; ++ot)
        #pragma unroll
        for (int kt = 0; kt < 4; ++kt)
            wf[ot][kt] = *(const v4i*)(wq + (size_t)(obase + ot * 16 + lr) * 256 + kt * 64 + quad * 16);

    // ---- quantize acts rows 0..63 -> LDS ----
    #pragma unroll
    for (int j = 0; j < 8; ++j) {
        int idx = j * 512 + tid;            // float4 flat index (0..4095)
        int row = idx >> 6, c = idx & 63;   // 64 float4 per row
        int b0 = (int)rintf(fminf(fmaxf(f[j][0], 0.f), 1.f) * 15.f);
        int b1 = (int)rintf(fminf(fmaxf(f[j][1], 0.f), 1.f) * 15.f);
        int b2 = (int)rintf(fminf(fmaxf(f[j][2], 0.f), 1.f) * 15.f);
        int b3 = (int)rintf(fminf(fmaxf(f[j][3], 0.f), 1.f) * 15.f);
        *(int*)(ldsx + row * 272 + c * 4) = b0 | (b1 << 8) | (b2 << 16) | (b3 << 24);
    }
    // ---- x loads + quantize rows 64..127 ----
    #pragma unroll
    for (int j = 0; j < 8; ++j)
        f[j] = xb[4096 + j * 512 + tid];
    #pragma unroll
    for (int j = 0; j < 8; ++j) {
        int idx = j * 512 + tid;
        int row = 64 + (idx >> 6), c = idx & 63;
        int b0 = (int)rintf(fminf(fmaxf(f[j][0], 0.f), 1.f) * 15.f);
        int b1 = (int)rintf(fminf(fmaxf(f[j][1], 0.f), 1.f) * 15.f);
        int b2 = (int)rintf(fminf(fmaxf(f[j][2], 0.f), 1.f) * 15.f);
        int b3 = (int)rintf(fminf(fmaxf(f[j][3], 0.f), 1.f) * 15.f);
        *(int*)(ldsx + row * 272 + c * 4) = b0 | (b1 << 8) | (b2 << 16) | (b3 << 24);
    }
    __syncthreads();   // the ONLY block barrier in phase 1

    int ssum[2][4] = {{0,0,0,0},{0,0,0,0}};
    int ssq [2][4] = {{0,0,0,0},{0,0,0,0}};
    unsigned spack[16];   // s values packed 4-per-dword, all indices compile-time

    #pragma unroll
    for (int t = 0; t < 8; ++t) {
        v4i a[4];
        #pragma unroll
        for (int kt = 0; kt < 4; ++kt)
            a[kt] = *(const v4i*)(ldsx + (t * 16 + lr) * 272 + kt * 64 + quad * 16);
        #pragma unroll
        for (int ot = 0; ot < 2; ++ot) {
            v4i acc0 = {0, 0, 0, 0}, acc1 = {0, 0, 0, 0};
            // D[r=channel][c=batchrow]: A = weights, B = acts (swapped)
            acc0 = __builtin_amdgcn_mfma_i32_16x16x64_i8(wf[ot][0], a[0], acc0, 0, 0, 0);
            acc0 = __builtin_amdgcn_mfma_i32_16x16x64_i8(wf[ot][1], a[1], acc0, 0, 0, 0);
            acc1 = __builtin_amdgcn_mfma_i32_16x16x64_i8(wf[ot][2], a[2], acc1, 0, 0, 0);
            acc1 = __builtin_amdgcn_mfma_i32_16x16x64_i8(wf[ot][3], a[3], acc1, 0, 0, 0);
            unsigned pack = 0;
            #pragma unroll
            for (int e = 0; e < 4; ++e) {
                int s = rhe1792(acc0[e]) + rhe1792(acc1[e]);   // exact, in [-16,16]
                ssum[ot][e] += s;
                ssq [ot][e] += s * s;
                pack |= (unsigned)(s & 255) << (8 * e);
            }
            spack[t * 2 + ot] = pack;
        }
    }

    // ---- per-channel stats: reduce across the 16 lr-lanes, atomics to replicas ----
    {
        int* st = stats + (blockIdx.x & (NREP - 1)) * 512;
        #pragma unroll
        for (int ot = 0; ot < 2; ++ot)
            #pragma unroll
            for (int e = 0; e < 4; ++e) {
                int v = ssum[ot][e], u = ssq[ot][e];
                v += __shfl_xor(v, 1, 64); v += __shfl_xor(v, 2, 64);
                v += __shfl_xor(v, 4, 64); v += __shfl_xor(v, 8, 64);
                u += __shfl_xor(u, 1, 64); u += __shfl_xor(u, 2, 64);
                u += __shfl_xor(u, 4, 64); u += __shfl_xor(u, 8, 64);
                if (lr == 0) {
                    int ch = obase + ot * 16 + quad * 4 + e;
                    atomicAdd(&st[ch], v);
                    atomicAdd(&st[256 + ch], u);
                }
            }
    }

    cg::this_grid().sync();   // all stats final; release/acquire at device scope

    // ---- BN affine per block (once, 256 channels), exact integer stats ----
    if (tid < 256) {
        const int o = tid;
        int s = 0, q = 0;
        #pragma unroll
        for (int rr = 0; rr < NREP; ++rr) {
            s += __hip_atomic_load(&stats[rr * 512 + o],       __ATOMIC_RELAXED, __HIP_MEMORY_SCOPE_AGENT);
            q += __hip_atomic_load(&stats[rr * 512 + 256 + o], __ATOMIC_RELAXED, __HIP_MEMORY_SCOPE_AGENT);
        }
        float scale_w = reduce_partials(partials, o) / 7.0f;
        float t = scale_w / 15.0f;                 // ref: scale_w / qmax_a in f32
        double Cs = 1792.0 * (double)t;            // acc = s * Cs
        const double N = 65536.0;
        double mean_s = (double)s / N;
        double var_s  = (double)q / N - mean_s * mean_s;
        double var    = Cs * Cs * var_s;
        double inv    = 1.0 / sqrt(var + 1e-5);
        double A = Cs * inv * (double)gamma[o];
        double B = (double)beta[o] - Cs * mean_s * inv * (double)gamma[o];
        abA[o] = (float)A;
        abB[o] = (float)B;
    }
    __syncthreads();

    // ---- epilogue from registers: float4 per (t,ot), fully 64B-granular ----
    const float inv15 = 0.066666666666666666f;
    #pragma unroll
    for (int t = 0; t < 8; ++t)
        #pragma unroll
        for (int ot = 0; ot < 2; ++ot) {
            unsigned pk = spack[t * 2 + ot];
            const int ch0 = obase + ot * 16 + quad * 4;
            v4f A4 = *(const v4f*)&abA[ch0];     // 4-lane broadcast reads, conflict-free
            v4f B4 = *(const v4f*)&abB[ch0];
            v4f o4;
            #pragma unroll
            for (int e = 0; e < 4; ++e) {
                float v = (float)((int)(pk << (24 - 8 * e)) >> 24);
                o4[e] = rintf(fminf(fmaxf(v * A4[e] + B4[e], 0.f), 1.f) * 15.f) * inv15;
            }
            const size_t grow = rb0 + (size_t)t * 16 + lr;
            __builtin_nontemporal_store(o4, (v4f*)out + grow * 64 + (ch0 >> 2));
        }
}

// =================== fallback path (old proven 2-kernel pipeline) ===================
template <typename ST>
__global__ __launch_bounds__(512, 4) void k_gemm(
    const float* __restrict__ x, const signed char* __restrict__ wq,
    ST* __restrict__ sbuf, int* __restrict__ stats)
{
    __shared__ __align__(16) signed char ldsx[64 * 272];
    const int tid  = threadIdx.x;
    const int lane = tid & 63;
    const int wv   = tid >> 6;
    const int obase = wv * 32;
    const int lr = lane & 15, quad = lane >> 4;
    const size_t rb0 = (size_t)blockIdx.x * 64;

    v4f f[8];
    const v4f* xb = (const v4f*)(x + rb0 * 256);
    #pragma unroll
    for (int j = 0; j < 8; ++j)
        f[j] = xb[j * 512 + tid];

    v4i wf[2][4];
    #pragma unroll
    for (int ot = 0; ot < 2; ++ot)
        #pragma unroll
        for (int kt = 0; kt < 4; ++kt)
            wf[ot][kt] = *(const v4i*)(wq + (size_t)(obase + ot * 16 + lr) * 256 + kt * 64 + quad * 16);

    #pragma unroll
    for (int j = 0; j < 8; ++j) {
        int idx = j * 512 + tid;
        int row = idx >> 6, c = idx & 63;
        int b0 = (int)rintf(fminf(fmaxf(f[j][0], 0.f), 1.f) * 15.f);
        int b1 = (int)rintf(fminf(fmaxf(f[j][1], 0.f), 1.f) * 15.f);
        int b2 = (int)rintf(fminf(fmaxf(f[j][2], 0.f), 1.f) * 15.f);
        int b3 = (int)rintf(fminf(fmaxf(f[j][3], 0.f), 1.f) * 15.f);
        *(int*)(ldsx + row * 272 + c * 4) = b0 | (b1 << 8) | (b2 << 16) | (b3 << 24);
    }
    __syncthreads();

    int ssum[2] = {0, 0};
    int ssq[2]  = {0, 0};

    #pragma unroll
    for (int t = 0; t < 4; ++t) {
        v4i a[4];
        #pragma unroll
        for (int kt = 0; kt < 4; ++kt)
            a[kt] = *(const v4i*)(ldsx + (t * 16 + lr) * 272 + kt * 64 + quad * 16);
        #pragma unroll
        for (int ot = 0; ot < 2; ++ot) {
            v4i acc0 = {0, 0, 0, 0}, acc1 = {0, 0, 0, 0};
            acc0 = __builtin_amdgcn_mfma_i32_16x16x64_i8(a[0], wf[ot][0], acc0, 0, 0, 0);
            acc0 = __builtin_amdgcn_mfma_i32_16x16x64_i8(a[1], wf[ot][1], acc0, 0, 0, 0);
            acc1 = __builtin_amdgcn_mfma_i32_16x16x64_i8(a[2], wf[ot][2], acc1, 0, 0, 0);
            acc1 = __builtin_amdgcn_mfma_i32_16x16x64_i8(a[3], wf[ot][3], acc1, 0, 0, 0);
            const int ocol = obase + ot * 16 + lr;
            if constexpr (sizeof(ST) == 1) {
                unsigned pack = 0;
                #pragma unroll
                for (int e = 0; e < 4; ++e) {
                    int s = rhe1792(acc0[e]) + rhe1792(acc1[e]);
                    ssum[ot] += s;
                    ssq[ot]  += s * s;
                    pack |= (unsigned)(s & 255) << (8 * e);
                }
                const size_t rg = (size_t)blockIdx.x * 16 + t * 4 + quad;
                ((unsigned*)sbuf)[rg * 256 + ocol] = pack;
            } else {
                ST* sp = sbuf + (rb0 + (size_t)t * 16 + quad * 4) * 256 + ocol;
                #pragma unroll
                for (int e = 0; e < 4; ++e) {
                    int s = rhe1792(acc0[e]) + rhe1792(acc1[e]);
                    ssum[ot] += s;
                    ssq[ot]  += s * s;
                    sp[(size_t)e * 256] = (ST)s;
                }
            }
        }
    }
    int* st = stats + (blockIdx.x & (NREP - 1)) * 512;
    #pragma unroll
    for (int ot = 0; ot < 2; ++ot) {
        int v = ssum[ot], u = ssq[ot];
        v += __shfl_xor(v, 16, 64); v += __shfl_xor(v, 32, 64);
        u += __shfl_xor(u, 16, 64); u += __shfl_xor(u, 32, 64);
        if (quad == 0) {
            atomicAdd(&st[obase + ot * 16 + lr], v);
            atomicAdd(&st[256 + obase + ot * 16 + lr], u);
        }
    }
}

template <typename LT>
__global__ __launch_bounds__(256) void k_out(const LT* sbuf, const int* __restrict__ stats,
                                             const float* __restrict__ partials,
                                             const float* __restrict__ gamma,
                                             const float* __restrict__ beta,
                                             float* out)
{
    __shared__ float2 ab[256];
    const int tid = threadIdx.x;
    {
        int o = tid;
        int s = 0, q = 0;
        #pragma unroll
        for (int rr = 0; rr < NREP; ++rr) {
            s += stats[rr * 512 + o];
            q += stats[rr * 512 + 256 + o];
        }
        float scale_w = reduce_partials(partials, o) / 7.0f;
        float t = scale_w / 15.0f;
        double Cs = 1792.0 * (double)t;
        const double N = 65536.0;
        double mean_s = (double)s / N;
        double var_s  = (double)q / N - mean_s * mean_s;
        double var    = Cs * Cs * var_s;
        double inv    = 1.0 / sqrt(var + 1e-5);
        double A = Cs * inv * (double)gamma[o];
        double B = (double)beta[o] - Cs * mean_s * inv * (double)gamma[o];
        ab[o] = make_float2((float)A, (float)B);
    }
    __syncthreads();

    const int b = blockIdx.x;
    const int d = ((b & 7) << 2) | ((b >> 3) & 3) | (b & ~31);
    const int ci = tid & 63;
    const int c0 = ci * 4;
    const float2 p0 = ab[c0], p1 = ab[c0 + 1], p2 = ab[c0 + 2], p3 = ab[c0 + 3];
    const float inv15 = 0.066666666666666666f;

    if constexpr (sizeof(LT) == 1) {
        const int rg = d * 4 + (tid >> 6);
        v4i V = ((const v4i*)sbuf)[(size_t)rg * 64 + ci];
        #pragma unroll
        for (int j = 0; j < 4; ++j) {
            float v0 = (float)((V[0] << (24 - 8 * j)) >> 24);
            float v1 = (float)((V[1] << (24 - 8 * j)) >> 24);
            float v2 = (float)((V[2] << (24 - 8 * j)) >> 24);
            float v3 = (float)((V[3] << (24 - 8 * j)) >> 24);
            float y0 = rintf(fminf(fmaxf(v0 * p0.x + p0.y, 0.f), 1.f) * 15.f);
            float y1 = rintf(fminf(fmaxf(v1 * p1.x + p1.y, 0.f), 1.f) * 15.f);
            float y2 = rintf(fminf(fmaxf(v2 * p2.x + p2.y, 0.f), 1.f) * 15.f);
            float y3 = rintf(fminf(fmaxf(v3 * p3.x + p3.y, 0.f), 1.f) * 15.f);
            v4f o = { y0 * inv15, y1 * inv15, y2 * inv15, y3 * inv15 };
            __builtin_nontemporal_store(o, (v4f*)out + (size_t)(4 * rg + j) * 64 + ci);
        }
    } else {
        const size_t base = (size_t)d * 1024 + tid;
        #pragma unroll
        for (int j = 0; j < 4; ++j) {
            const size_t F4 = base + (size_t)j * 256;
            v4f fl = ((const v4f*)sbuf)[F4];
            const int oo = (tid * 4) & 255;
            float2 q0 = ab[oo], q1 = ab[oo + 1], q2 = ab[oo + 2], q3 = ab[oo + 3];
            float y0 = rintf(fminf(fmaxf(fl[0] * q0.x + q0.y, 0.f), 1.f) * 15.f);
            float y1 = rintf(fminf(fmaxf(fl[1] * q1.x + q1.y, 0.f), 1.f) * 15.f);
            float y2 = rintf(fminf(fmaxf(fl[2] * q2.x + q2.y, 0.f), 1.f) * 15.f);
            float y3 = rintf(fminf(fmaxf(fl[3] * q3.x + q3.y, 0.f), 1.f) * 15.f);
            v4f o = { y0 * inv15, y1 * inv15, y2 * inv15, y3 * inv15 };
            __builtin_nontemporal_store(o, (v4f*)out + F4);
        }
    }
}

// ---------------- launch ----------------
extern "C" void kernel_launch(void* const* d_in, const int* in_sizes, int n_in,
                              void* d_out, int out_size, void* d_ws, size_t ws_size,
                              hipStream_t stream)
{
    const float* x     = (const float*)d_in[0];
    const float* w     = (const float*)d_in[1];
    const float* gamma = (const float*)d_in[2];
    const float* beta  = (const float*)d_in[3];
    float* out = (float*)d_out;
    char* ws = (char*)d_ws;

    signed char* wq       = (signed char*)(ws + WQ_OFF);
    int*         stats    = (int*)(ws + STATS_OFF);
    float*       partials = (float*)(ws + PART_OFF);

    k_maxabs<<<dim3(64), dim3(256), 0, stream>>>(w, partials, stats);
    k_wquant<<<dim3(64), dim3(256), 0, stream>>>(w, partials, wq);

    hipError_t err = hipErrorUnknown;
    if (ws_size >= WS_MIN) {
        void* kargs[] = { (void*)&x, (void*)&wq, (void*)&partials, (void*)&stats,
                          (void*)&gamma, (void*)&beta, (void*)&out };
        err = hipLaunchCooperativeKernel((const void*)k_fused, dim3(512), dim3(512),
                                         kargs, 0, stream);
    }
    if (err != hipSuccess) {
        // fallback: old proven 4-kernel pipeline
        if (ws_size >= WS_SBUF_NEEDED) {
            signed char* sbuf = (signed char*)(ws + SBUF_OFF);
            k_gemm<signed char><<<dim3(1024), dim3(512), 0, stream>>>(x, wq, sbuf, stats);
            k_out<signed char><<<dim3(4096), dim3(256), 0, stream>>>(sbuf, stats, partials,
                                                                     gamma, beta, out);
        } else {
            k_gemm<float><<<dim3(1024), dim3(512), 0, stream>>>(x, wq, out, stats);
            k_out<float><<<dim3(4096), dim3(256), 0, stream>>>(out, stats, partials,
                                                               gamma, beta, out);
        }
    }
}

// Round 3
// 235.636 us; speedup vs baseline: 1.0117x; 1.0117x over previous
//
#include <hip/hip_runtime.h>
#include <hip/hip_cooperative_groups.h>
#include <cstdint>
#include <cstddef>

namespace cg = cooperative_groups;

typedef int   v4i __attribute__((ext_vector_type(4)));
typedef float v4f __attribute__((ext_vector_type(4)));

static constexpr int NREP = 8;    // stats replica count (atomic contention spreading)

// ---------------- workspace layout (bytes) ----------------
static constexpr size_t WQ_OFF    = 0;                        // 65536 int8 weights
static constexpr size_t STATS_OFF = 65536;                    // NREP*512 int32 = 16384
static constexpr size_t PART_OFF  = STATS_OFF + NREP*512*4;   // 64 floats
static constexpr size_t SBUF_OFF  = 131072 + 2048;            // 16 MiB s-values (fallback path)
static constexpr size_t WS_SBUF_NEEDED = SBUF_OFF + (size_t)65536 * 256;
static constexpr size_t WS_MIN    = PART_OFF + 64 * 4;        // cooperative path needs only this

// exact round-half-even of p/1792 for |p| <= 13440 (1792 = 7*256)
__device__ __forceinline__ int rhe1792(int p) {
    unsigned u = (unsigned)(p + 17024);      // (p+896) + 9*1792, u in [3584,30464]
    unsigned v = u >> 8;                     // floor(u/256), in [14,119]
    unsigned d = (v * 147u) >> 10;           // floor(v/7), exact for v<=119
    int q = (int)d - 9;                      // round-half-up(p/1792)
    unsigned tie = (unsigned)(((u & 255u) | (v - 7u * d)) == 0u);
    q -= (int)(tie & ((unsigned)q & 1u));    // half-even: ties round to even
    return q;
}

// ---------------- k1: per-block max|w| partials + zero stats ----------------
__global__ void k_maxabs(const float* __restrict__ w, float* __restrict__ partials,
                         int* __restrict__ stats) {
    __shared__ float wmax[4];
    int idx = blockIdx.x * 256 + threadIdx.x;     // 64 blocks * 256 = 16384 float4
    float4 f = ((const float4*)w)[idx];
    float m = fmaxf(fmaxf(fabsf(f.x), fabsf(f.y)), fmaxf(fabsf(f.z), fabsf(f.w)));
    #pragma unroll
    for (int s = 32; s > 0; s >>= 1) m = fmaxf(m, __shfl_xor(m, s, 64));
    if ((threadIdx.x & 63) == 0) wmax[threadIdx.x >> 6] = m;
    if (idx < NREP * 512) stats[idx] = 0;         // zero replicas
    __syncthreads();
    if (threadIdx.x == 0)
        partials[blockIdx.x] = fmaxf(fmaxf(wmax[0], wmax[1]), fmaxf(wmax[2], wmax[3]));
}

// wave-redundant reduce of the 64 partials (L2-hot) -> global max|w|
__device__ __forceinline__ float reduce_partials(const float* __restrict__ partials, int tid) {
    float p = partials[tid & 63];
    #pragma unroll
    for (int s = 32; s > 0; s >>= 1) p = fmaxf(p, __shfl_xor(p, s, 64));
    return p;
}

// ---------------- k2: quantize weights to int8 ----------------
__global__ void k_wquant(const float* __restrict__ w, const float* __restrict__ partials,
                         signed char* __restrict__ wq) {
    int idx = blockIdx.x * 256 + threadIdx.x;
    float scale = reduce_partials(partials, threadIdx.x) / 7.0f;  // scale_w (f32 div, as ref)
    float4 f = ((const float4*)w)[idx];
    int q0 = (int)rintf(fminf(fmaxf(f.x / scale, -7.f), 7.f));
    int q1 = (int)rintf(fminf(fmaxf(f.y / scale, -7.f), 7.f));
    int q2 = (int)rintf(fminf(fmaxf(f.z / scale, -7.f), 7.f));
    int q3 = (int)rintf(fminf(fmaxf(f.w / scale, -7.f), 7.f));
    ((int*)wq)[idx] = (q0 & 255) | ((q1 & 255) << 8) | ((q2 & 255) << 16) | ((q3 & 255) << 24);
}

// ---------------- k3 (cooperative): GEMM + stats, grid.sync, BN + output ----
// 512 blocks x 256 threads (4 waves), 128 batch rows/block, s held IN REGISTERS
// across the grid sync (no sbuf round-trip). MFMA operands swapped (A=weights,
// B=acts): C row = channel (quad*4+e), col = batch row (lr) -> float4 stores.
// Residency: __launch_bounds__(256, 2) -> 256-VGPR budget, 2 blocks/CU needs
// only 8 waves/CU (2/SIMD). Register demand ~170 sits mid-plateau (129..256 all
// give 2 blocks/CU), LDS 36.9KB*2 << 160KB -> NO exact-fit cliff (round-2
// lesson: (512,2) = 128-reg cap + exactly-2-blocks was deadlock-fragile).
// Each wave owns 64 channels: wf[4][4] (64 VGPR), spack[32], ssum/ssq[4][4].
__global__ __launch_bounds__(256, 2) void k_fused(
    const float* __restrict__ x, const signed char* __restrict__ wq,
    const float* __restrict__ partials, int* __restrict__ stats,
    const float* __restrict__ gamma, const float* __restrict__ beta,
    float* __restrict__ out)
{
    __shared__ __align__(16) signed char ldsx[128 * 272];  // 128 rows x 256 k (+16B pad/row)
    __shared__ __align__(16) float abA[256];
    __shared__ __align__(16) float abB[256];

    const int tid  = threadIdx.x;
    const int lane = tid & 63;
    const int wv   = tid >> 6;            // 0..3
    const int obase = wv * 64;            // 64 channels per wave
    const int lr = lane & 15, quad = lane >> 4;
    const size_t rb0 = (size_t)blockIdx.x * 128;

    // ---- weight fragments first (L2-hot, persist): A row = channel, k = kt*64+quad*16+i
    v4i wf[4][4];
    #pragma unroll
    for (int ot = 0; ot < 4; ++ot)
        #pragma unroll
        for (int kt = 0; kt < 4; ++kt)
            wf[ot][kt] = *(const v4i*)(wq + (size_t)(obase + ot * 16 + lr) * 256 + kt * 64 + quad * 16);

    // ---- stage x -> quantize -> LDS, 4 passes of 8 float4/thread ----
    const v4f* xb = (const v4f*)(x + rb0 * 256);
    #pragma unroll
    for (int p = 0; p < 4; ++p) {
        v4f f[8];
        #pragma unroll
        for (int j = 0; j < 8; ++j)
            f[j] = xb[p * 2048 + j * 256 + tid];
        #pragma unroll
        for (int j = 0; j < 8; ++j) {
            int idx = p * 2048 + j * 256 + tid;   // float4 flat index (0..8191)
            int row = idx >> 6, c = idx & 63;     // 64 float4 per row
            int b0 = (int)rintf(fminf(fmaxf(f[j][0], 0.f), 1.f) * 15.f);
            int b1 = (int)rintf(fminf(fmaxf(f[j][1], 0.f), 1.f) * 15.f);
            int b2 = (int)rintf(fminf(fmaxf(f[j][2], 0.f), 1.f) * 15.f);
            int b3 = (int)rintf(fminf(fmaxf(f[j][3], 0.f), 1.f) * 15.f);
            *(int*)(ldsx + row * 272 + c * 4) = b0 | (b1 << 8) | (b2 << 16) | (b3 << 24);
        }
    }
    __syncthreads();   // the ONLY block barrier in phase 1

    int ssum[4][4] = {};
    int ssq [4][4] = {};
    unsigned spack[32];   // s packed 4-per-dword, all indices compile-time

    #pragma unroll
    for (int t = 0; t < 8; ++t) {
        v4i a[4];
        #pragma unroll
        for (int kt = 0; kt < 4; ++kt)
            a[kt] = *(const v4i*)(ldsx + (t * 16 + lr) * 272 + kt * 64 + quad * 16);
        #pragma unroll
        for (int ot = 0; ot < 4; ++ot) {
            v4i acc0 = {0, 0, 0, 0}, acc1 = {0, 0, 0, 0};
            // D[r=channel][c=batchrow]: A = weights, B = acts (swapped)
            acc0 = __builtin_amdgcn_mfma_i32_16x16x64_i8(wf[ot][0], a[0], acc0, 0, 0, 0);
            acc0 = __builtin_amdgcn_mfma_i32_16x16x64_i8(wf[ot][1], a[1], acc0, 0, 0, 0);
            acc1 = __builtin_amdgcn_mfma_i32_16x16x64_i8(wf[ot][2], a[2], acc1, 0, 0, 0);
            acc1 = __builtin_amdgcn_mfma_i32_16x16x64_i8(wf[ot][3], a[3], acc1, 0, 0, 0);
            unsigned pack = 0;
            #pragma unroll
            for (int e = 0; e < 4; ++e) {
                int s = rhe1792(acc0[e]) + rhe1792(acc1[e]);   // exact, in [-16,16]
                ssum[ot][e] += s;
                ssq [ot][e] += s * s;
                pack |= (unsigned)(s & 255) << (8 * e);
            }
            spack[t * 4 + ot] = pack;
        }
    }

    // ---- per-channel stats: reduce across the 16 lr-lanes, atomics to replicas ----
    {
        int* st = stats + (blockIdx.x & (NREP - 1)) * 512;
        #pragma unroll
        for (int ot = 0; ot < 4; ++ot)
            #pragma unroll
            for (int e = 0; e < 4; ++e) {
                int v = ssum[ot][e], u = ssq[ot][e];
                v += __shfl_xor(v, 1, 64); v += __shfl_xor(v, 2, 64);
                v += __shfl_xor(v, 4, 64); v += __shfl_xor(v, 8, 64);
                u += __shfl_xor(u, 1, 64); u += __shfl_xor(u, 2, 64);
                u += __shfl_xor(u, 4, 64); u += __shfl_xor(u, 8, 64);
                if (lr == 0) {
                    int ch = obase + ot * 16 + quad * 4 + e;
                    atomicAdd(&st[ch], v);
                    atomicAdd(&st[256 + ch], u);
                }
            }
    }

    cg::this_grid().sync();   // all stats final; release/acquire at device scope

    // ---- BN affine (one channel per thread), exact integer stats ----
    {
        const int o = tid;
        int s = 0, q = 0;
        #pragma unroll
        for (int rr = 0; rr < NREP; ++rr) {
            s += __hip_atomic_load(&stats[rr * 512 + o],       __ATOMIC_RELAXED, __HIP_MEMORY_SCOPE_AGENT);
            q += __hip_atomic_load(&stats[rr * 512 + 256 + o], __ATOMIC_RELAXED, __HIP_MEMORY_SCOPE_AGENT);
        }
        float scale_w = reduce_partials(partials, o) / 7.0f;
        float t = scale_w / 15.0f;                 // ref: scale_w / qmax_a in f32
        double Cs = 1792.0 * (double)t;            // acc = s * Cs
        const double N = 65536.0;
        double mean_s = (double)s / N;
        double var_s  = (double)q / N - mean_s * mean_s;
        double var    = Cs * Cs * var_s;
        double inv    = 1.0 / sqrt(var + 1e-5);
        double A = Cs * inv * (double)gamma[o];
        double B = (double)beta[o] - Cs * mean_s * inv * (double)gamma[o];
        abA[o] = (float)A;
        abB[o] = (float)B;
    }
    __syncthreads();

    // ---- epilogue from registers: float4 per (t,ot), 64B clusters per row ----
    const float inv15 = 0.066666666666666666f;
    #pragma unroll
    for (int t = 0; t < 8; ++t)
        #pragma unroll
        for (int ot = 0; ot < 4; ++ot) {
            unsigned pk = spack[t * 4 + ot];
            const int ch0 = obase + ot * 16 + quad * 4;
            v4f A4 = *(const v4f*)&abA[ch0];     // 4-lane broadcast reads, conflict-free
            v4f B4 = *(const v4f*)&abB[ch0];
            v4f o4;
            #pragma unroll
            for (int e = 0; e < 4; ++e) {
                float v = (float)((int)(pk << (24 - 8 * e)) >> 24);
                o4[e] = rintf(fminf(fmaxf(v * A4[e] + B4[e], 0.f), 1.f) * 15.f) * inv15;
            }
            const size_t grow = rb0 + (size_t)t * 16 + lr;
            __builtin_nontemporal_store(o4, (v4f*)out + grow * 64 + (ch0 >> 2));
        }
}

// =================== fallback path (old proven 2-kernel pipeline) ===================
template <typename ST>
__global__ __launch_bounds__(512, 4) void k_gemm(
    const float* __restrict__ x, const signed char* __restrict__ wq,
    ST* __restrict__ sbuf, int* __restrict__ stats)
{
    __shared__ __align__(16) signed char ldsx[64 * 272];
    const int tid  = threadIdx.x;
    const int lane = tid & 63;
    const int wv   = tid >> 6;
    const int obase = wv * 32;
    const int lr = lane & 15, quad = lane >> 4;
    const size_t rb0 = (size_t)blockIdx.x * 64;

    v4f f[8];
    const v4f* xb = (const v4f*)(x + rb0 * 256);
    #pragma unroll
    for (int j = 0; j < 8; ++j)
        f[j] = xb[j * 512 + tid];

    v4i wf[2][4];
    #pragma unroll
    for (int ot = 0; ot < 2; ++ot)
        #pragma unroll
        for (int kt = 0; kt < 4; ++kt)
            wf[ot][kt] = *(const v4i*)(wq + (size_t)(obase + ot * 16 + lr) * 256 + kt * 64 + quad * 16);

    #pragma unroll
    for (int j = 0; j < 8; ++j) {
        int idx = j * 512 + tid;
        int row = idx >> 6, c = idx & 63;
        int b0 = (int)rintf(fminf(fmaxf(f[j][0], 0.f), 1.f) * 15.f);
        int b1 = (int)rintf(fminf(fmaxf(f[j][1], 0.f), 1.f) * 15.f);
        int b2 = (int)rintf(fminf(fmaxf(f[j][2], 0.f), 1.f) * 15.f);
        int b3 = (int)rintf(fminf(fmaxf(f[j][3], 0.f), 1.f) * 15.f);
        *(int*)(ldsx + row * 272 + c * 4) = b0 | (b1 << 8) | (b2 << 16) | (b3 << 24);
    }
    __syncthreads();

    int ssum[2] = {0, 0};
    int ssq[2]  = {0, 0};

    #pragma unroll
    for (int t = 0; t < 4; ++t) {
        v4i a[4];
        #pragma unroll
        for (int kt = 0; kt < 4; ++kt)
            a[kt] = *(const v4i*)(ldsx + (t * 16 + lr) * 272 + kt * 64 + quad * 16);
        #pragma unroll
        for (int ot = 0; ot < 2; ++ot) {
            v4i acc0 = {0, 0, 0, 0}, acc1 = {0, 0, 0, 0};
            acc0 = __builtin_amdgcn_mfma_i32_16x16x64_i8(a[0], wf[ot][0], acc0, 0, 0, 0);
            acc0 = __builtin_amdgcn_mfma_i32_16x16x64_i8(a[1], wf[ot][1], acc0, 0, 0, 0);
            acc1 = __builtin_amdgcn_mfma_i32_16x16x64_i8(a[2], wf[ot][2], acc1, 0, 0, 0);
            acc1 = __builtin_amdgcn_mfma_i32_16x16x64_i8(a[3], wf[ot][3], acc1, 0, 0, 0);
            const int ocol = obase + ot * 16 + lr;
            if constexpr (sizeof(ST) == 1) {
                unsigned pack = 0;
                #pragma unroll
                for (int e = 0; e < 4; ++e) {
                    int s = rhe1792(acc0[e]) + rhe1792(acc1[e]);
                    ssum[ot] += s;
                    ssq[ot]  += s * s;
                    pack |= (unsigned)(s & 255) << (8 * e);
                }
                const size_t rg = (size_t)blockIdx.x * 16 + t * 4 + quad;
                ((unsigned*)sbuf)[rg * 256 + ocol] = pack;
            } else {
                ST* sp = sbuf + (rb0 + (size_t)t * 16 + quad * 4) * 256 + ocol;
                #pragma unroll
                for (int e = 0; e < 4; ++e) {
                    int s = rhe1792(acc0[e]) + rhe1792(acc1[e]);
                    ssum[ot] += s;
                    ssq[ot]  += s * s;
                    sp[(size_t)e * 256] = (ST)s;
                }
            }
        }
    }
    int* st = stats + (blockIdx.x & (NREP - 1)) * 512;
    #pragma unroll
    for (int ot = 0; ot < 2; ++ot) {
        int v = ssum[ot], u = ssq[ot];
        v += __shfl_xor(v, 16, 64); v += __shfl_xor(v, 32, 64);
        u += __shfl_xor(u, 16, 64); u += __shfl_xor(u, 32, 64);
        if (quad == 0) {
            atomicAdd(&st[obase + ot * 16 + lr], v);
            atomicAdd(&st[256 + obase + ot * 16 + lr], u);
        }
    }
}

template <typename LT>
__global__ __launch_bounds__(256) void k_out(const LT* sbuf, const int* __restrict__ stats,
                                             const float* __restrict__ partials,
                                             const float* __restrict__ gamma,
                                             const float* __restrict__ beta,
                                             float* out)
{
    __shared__ float2 ab[256];
    const int tid = threadIdx.x;
    {
        int o = tid;
        int s = 0, q = 0;
        #pragma unroll
        for (int rr = 0; rr < NREP; ++rr) {
            s += stats[rr * 512 + o];
            q += stats[rr * 512 + 256 + o];
        }
        float scale_w = reduce_partials(partials, o) / 7.0f;
        float t = scale_w / 15.0f;
        double Cs = 1792.0 * (double)t;
        const double N = 65536.0;
        double mean_s = (double)s / N;
        double var_s  = (double)q / N - mean_s * mean_s;
        double var    = Cs * Cs * var_s;
        double inv    = 1.0 / sqrt(var + 1e-5);
        double A = Cs * inv * (double)gamma[o];
        double B = (double)beta[o] - Cs * mean_s * inv * (double)gamma[o];
        ab[o] = make_float2((float)A, (float)B);
    }
    __syncthreads();

    const int b = blockIdx.x;
    const int d = ((b & 7) << 2) | ((b >> 3) & 3) | (b & ~31);
    const int ci = tid & 63;
    const int c0 = ci * 4;
    const float2 p0 = ab[c0], p1 = ab[c0 + 1], p2 = ab[c0 + 2], p3 = ab[c0 + 3];
    const float inv15 = 0.066666666666666666f;

    if constexpr (sizeof(LT) == 1) {
        const int rg = d * 4 + (tid >> 6);
        v4i V = ((const v4i*)sbuf)[(size_t)rg * 64 + ci];
        #pragma unroll
        for (int j = 0; j < 4; ++j) {
            float v0 = (float)((V[0] << (24 - 8 * j)) >> 24);
            float v1 = (float)((V[1] << (24 - 8 * j)) >> 24);
            float v2 = (float)((V[2] << (24 - 8 * j)) >> 24);
            float v3 = (float)((V[3] << (24 - 8 * j)) >> 24);
            float y0 = rintf(fminf(fmaxf(v0 * p0.x + p0.y, 0.f), 1.f) * 15.f);
            float y1 = rintf(fminf(fmaxf(v1 * p1.x + p1.y, 0.f), 1.f) * 15.f);
            float y2 = rintf(fminf(fmaxf(v2 * p2.x + p2.y, 0.f), 1.f) * 15.f);
            float y3 = rintf(fminf(fmaxf(v3 * p3.x + p3.y, 0.f), 1.f) * 15.f);
            v4f o = { y0 * inv15, y1 * inv15, y2 * inv15, y3 * inv15 };
            __builtin_nontemporal_store(o, (v4f*)out + (size_t)(4 * rg + j) * 64 + ci);
        }
    } else {
        const size_t base = (size_t)d * 1024 + tid;
        #pragma unroll
        for (int j = 0; j < 4; ++j) {
            const size_t F4 = base + (size_t)j * 256;
            v4f fl = ((const v4f*)sbuf)[F4];
            const int oo = (tid * 4) & 255;
            float2 q0 = ab[oo], q1 = ab[oo + 1], q2 = ab[oo + 2], q3 = ab[oo + 3];
            float y0 = rintf(fminf(fmaxf(fl[0] * q0.x + q0.y, 0.f), 1.f) * 15.f);
            float y1 = rintf(fminf(fmaxf(fl[1] * q1.x + q1.y, 0.f), 1.f) * 15.f);
            float y2 = rintf(fminf(fmaxf(fl[2] * q2.x + q2.y, 0.f), 1.f) * 15.f);
            float y3 = rintf(fminf(fmaxf(fl[3] * q3.x + q3.y, 0.f), 1.f) * 15.f);
            v4f o = { y0 * inv15, y1 * inv15, y2 * inv15, y3 * inv15 };
            __builtin_nontemporal_store(o, (v4f*)out + F4);
        }
    }
}

// ---------------- launch ----------------
extern "C" void kernel_launch(void* const* d_in, const int* in_sizes, int n_in,
                              void* d_out, int out_size, void* d_ws, size_t ws_size,
                              hipStream_t stream)
{
    const float* x     = (const float*)d_in[0];
    const float* w     = (const float*)d_in[1];
    const float* gamma = (const float*)d_in[2];
    const float* beta  = (const float*)d_in[3];
    float* out = (float*)d_out;
    char* ws = (char*)d_ws;

    signed char* wq       = (signed char*)(ws + WQ_OFF);
    int*         stats    = (int*)(ws + STATS_OFF);
    float*       partials = (float*)(ws + PART_OFF);

    k_maxabs<<<dim3(64), dim3(256), 0, stream>>>(w, partials, stats);
    k_wquant<<<dim3(64), dim3(256), 0, stream>>>(w, partials, wq);

    hipError_t err = hipErrorUnknown;
    if (ws_size >= WS_MIN) {
        void* kargs[] = { (void*)&x, (void*)&wq, (void*)&partials, (void*)&stats,
                          (void*)&gamma, (void*)&beta, (void*)&out };
        err = hipLaunchCooperativeKernel((const void*)k_fused, dim3(512), dim3(256),
                                         kargs, 0, stream);
    }
    if (err != hipSuccess) {
        // fallback: old proven 4-kernel pipeline
        if (ws_size >= WS_SBUF_NEEDED) {
            signed char* sbuf = (signed char*)(ws + SBUF_OFF);
            k_gemm<signed char><<<dim3(1024), dim3(512), 0, stream>>>(x, wq, sbuf, stats);
            k_out<signed char><<<dim3(4096), dim3(256), 0, stream>>>(sbuf, stats, partials,
                                                                     gamma, beta, out);
        } else {
            k_gemm<float><<<dim3(1024), dim3(512), 0, stream>>>(x, wq, out, stats);
            k_out<float><<<dim3(4096), dim3(256), 0, stream>>>(out, stats, partials,
                                                               gamma, beta, out);
        }
    }
}

// Round 4
// 201.648 us; speedup vs baseline: 1.1822x; 1.1686x over previous
//
#include <hip/hip_runtime.h>
#include <hip/hip_cooperative_groups.h>
#include <cstdint>
#include <cstddef>

namespace cg = cooperative_groups;

typedef int   v4i __attribute__((ext_vector_type(4)));
typedef float v4f __attribute__((ext_vector_type(4)));

static constexpr int NREP = 8;    // stats replica count (atomic contention spreading)

// ---------------- workspace layout (bytes) ----------------
static constexpr size_t WQ_OFF    = 0;                        // 65536 int8 weights
static constexpr size_t STATS_OFF = 65536;                    // NREP*512 int32 = 16384
static constexpr size_t PART_OFF  = STATS_OFF + NREP*512*4;   // 64 floats
static constexpr size_t SBUF_OFF  = 131072 + 2048;            // 16 MiB s-values (fallback path)
static constexpr size_t WS_SBUF_NEEDED = SBUF_OFF + (size_t)65536 * 256;
static constexpr size_t WS_MIN    = PART_OFF + 64 * 4;        // cooperative path needs only this

// exact round-half-even of p/1792 for |p| <= 13440 (1792 = 7*256)
__device__ __forceinline__ int rhe1792(int p) {
    unsigned u = (unsigned)(p + 17024);      // (p+896) + 9*1792, u in [3584,30464]
    unsigned v = u >> 8;                     // floor(u/256), in [14,119]
    unsigned d = (v * 147u) >> 10;           // floor(v/7), exact for v<=119
    int q = (int)d - 9;                      // round-half-up(p/1792)
    unsigned tie = (unsigned)(((u & 255u) | (v - 7u * d)) == 0u);
    q -= (int)(tie & ((unsigned)q & 1u));    // half-even: ties round to even
    return q;
}

// ---------------- k1: per-block max|w| partials + zero stats ----------------
__global__ void k_maxabs(const float* __restrict__ w, float* __restrict__ partials,
                         int* __restrict__ stats) {
    __shared__ float wmax[4];
    int idx = blockIdx.x * 256 + threadIdx.x;     // 64 blocks * 256 = 16384 float4
    float4 f = ((const float4*)w)[idx];
    float m = fmaxf(fmaxf(fabsf(f.x), fabsf(f.y)), fmaxf(fabsf(f.z), fabsf(f.w)));
    #pragma unroll
    for (int s = 32; s > 0; s >>= 1) m = fmaxf(m, __shfl_xor(m, s, 64));
    if ((threadIdx.x & 63) == 0) wmax[threadIdx.x >> 6] = m;
    if (idx < NREP * 512) stats[idx] = 0;         // zero replicas
    __syncthreads();
    if (threadIdx.x == 0)
        partials[blockIdx.x] = fmaxf(fmaxf(wmax[0], wmax[1]), fmaxf(wmax[2], wmax[3]));
}

// wave-redundant reduce of the 64 partials (L2-hot) -> global max|w|
__device__ __forceinline__ float reduce_partials(const float* __restrict__ partials, int tid) {
    float p = partials[tid & 63];
    #pragma unroll
    for (int s = 32; s > 0; s >>= 1) p = fmaxf(p, __shfl_xor(p, s, 64));
    return p;
}

// ---------------- k2: quantize weights to int8 ----------------
__global__ void k_wquant(const float* __restrict__ w, const float* __restrict__ partials,
                         signed char* __restrict__ wq) {
    int idx = blockIdx.x * 256 + threadIdx.x;
    float scale = reduce_partials(partials, threadIdx.x) / 7.0f;  // scale_w (f32 div, as ref)
    float4 f = ((const float4*)w)[idx];
    int q0 = (int)rintf(fminf(fmaxf(f.x / scale, -7.f), 7.f));
    int q1 = (int)rintf(fminf(fmaxf(f.y / scale, -7.f), 7.f));
    int q2 = (int)rintf(fminf(fmaxf(f.z / scale, -7.f), 7.f));
    int q3 = (int)rintf(fminf(fmaxf(f.w / scale, -7.f), 7.f));
    ((int*)wq)[idx] = (q0 & 255) | ((q1 & 255) << 8) | ((q2 & 255) << 16) | ((q3 & 255) << 24);
}

// ---------------- k3 (cooperative): GEMM + stats, grid.sync, BN + output ----
// 256 blocks x 512 threads (8 waves), 256 batch rows/block, s held IN REGISTERS
// across the grid sync (no sbuf round-trip). MFMA operands swapped (A=weights,
// B=acts): C row = channel (quad*4+e), col = batch row (lr) -> float4 stores.
// Residency: grid 256 <= 256 CUs needs only 1 block/CU -> NO exact-fit cliff
// for any VGPR count <= 256 (rounds 1/3 lesson: HW cap = 2048/waves-per-CU;
// demanding more than the cap spills). Per-wave state shrunk back to 32
// channels: wf[2][4]=32 + spack[32]=32 + ssum/ssq=16 ~ 80 persistent VGPRs,
// peak ~115 -> no spills at any plausible cap. LDS 69.6KB < 160KB.
__global__ __launch_bounds__(512, 1) void k_fused(
    const float* __restrict__ x, const signed char* __restrict__ wq,
    const float* __restrict__ partials, int* __restrict__ stats,
    const float* __restrict__ gamma, const float* __restrict__ beta,
    float* __restrict__ out)
{
    __shared__ __align__(16) signed char ldsx[256 * 272];  // 256 rows x 256 k (+16B pad/row)
    __shared__ __align__(16) float abA[256];
    __shared__ __align__(16) float abB[256];

    const int tid  = threadIdx.x;
    const int lane = tid & 63;
    const int wv   = tid >> 6;            // 0..7
    const int obase = wv * 32;            // 32 channels per wave
    const int lr = lane & 15, quad = lane >> 4;
    const size_t rb0 = (size_t)blockIdx.x * 256;

    // ---- weight fragments (L2-hot): A row = channel, k = kt*64 + quad*16 + i ----
    v4i wf[2][4];
    #pragma unroll
    for (int ot = 0; ot < 2; ++ot)
        #pragma unroll
        for (int kt = 0; kt < 4; ++kt)
            wf[ot][kt] = *(const v4i*)(wq + (size_t)(obase + ot * 16 + lr) * 256 + kt * 64 + quad * 16);

    // ---- stage x -> quantize -> LDS, 4 passes of 8 float4/thread (256 rows) ----
    const v4f* xb = (const v4f*)(x + rb0 * 256);
    #pragma unroll
    for (int p = 0; p < 4; ++p) {
        v4f f[8];
        #pragma unroll
        for (int j = 0; j < 8; ++j)
            f[j] = xb[p * 4096 + j * 512 + tid];
        #pragma unroll
        for (int j = 0; j < 8; ++j) {
            int idx = p * 4096 + j * 512 + tid;   // float4 flat index (0..16383)
            int row = idx >> 6, c = idx & 63;     // 64 float4 per row
            int b0 = (int)rintf(fminf(fmaxf(f[j][0], 0.f), 1.f) * 15.f);
            int b1 = (int)rintf(fminf(fmaxf(f[j][1], 0.f), 1.f) * 15.f);
            int b2 = (int)rintf(fminf(fmaxf(f[j][2], 0.f), 1.f) * 15.f);
            int b3 = (int)rintf(fminf(fmaxf(f[j][3], 0.f), 1.f) * 15.f);
            *(int*)(ldsx + row * 272 + c * 4) = b0 | (b1 << 8) | (b2 << 16) | (b3 << 24);
        }
    }
    __syncthreads();   // the ONLY block barrier in phase 1

    int ssum[2][4] = {};
    int ssq [2][4] = {};
    unsigned spack[32];   // s packed 4-per-dword, all indices compile-time

    #pragma unroll
    for (int t = 0; t < 16; ++t) {
        v4i a[4];
        #pragma unroll
        for (int kt = 0; kt < 4; ++kt)
            a[kt] = *(const v4i*)(ldsx + (t * 16 + lr) * 272 + kt * 64 + quad * 16);
        #pragma unroll
        for (int ot = 0; ot < 2; ++ot) {
            v4i acc0 = {0, 0, 0, 0}, acc1 = {0, 0, 0, 0};
            // D[r=channel][c=batchrow]: A = weights, B = acts (swapped)
            acc0 = __builtin_amdgcn_mfma_i32_16x16x64_i8(wf[ot][0], a[0], acc0, 0, 0, 0);
            acc0 = __builtin_amdgcn_mfma_i32_16x16x64_i8(wf[ot][1], a[1], acc0, 0, 0, 0);
            acc1 = __builtin_amdgcn_mfma_i32_16x16x64_i8(wf[ot][2], a[2], acc1, 0, 0, 0);
            acc1 = __builtin_amdgcn_mfma_i32_16x16x64_i8(wf[ot][3], a[3], acc1, 0, 0, 0);
            unsigned pack = 0;
            #pragma unroll
            for (int e = 0; e < 4; ++e) {
                int s = rhe1792(acc0[e]) + rhe1792(acc1[e]);   // exact, in [-16,16]
                ssum[ot][e] += s;
                ssq [ot][e] += s * s;
                pack |= (unsigned)(s & 255) << (8 * e);
            }
            spack[t * 2 + ot] = pack;
        }
    }

    // ---- per-channel stats: reduce across the 16 lr-lanes, atomics to replicas ----
    {
        int* st = stats + (blockIdx.x & (NREP - 1)) * 512;
        #pragma unroll
        for (int ot = 0; ot < 2; ++ot)
            #pragma unroll
            for (int e = 0; e < 4; ++e) {
                int v = ssum[ot][e], u = ssq[ot][e];
                v += __shfl_xor(v, 1, 64); v += __shfl_xor(v, 2, 64);
                v += __shfl_xor(v, 4, 64); v += __shfl_xor(v, 8, 64);
                u += __shfl_xor(u, 1, 64); u += __shfl_xor(u, 2, 64);
                u += __shfl_xor(u, 4, 64); u += __shfl_xor(u, 8, 64);
                if (lr == 0) {
                    int ch = obase + ot * 16 + quad * 4 + e;
                    atomicAdd(&st[ch], v);
                    atomicAdd(&st[256 + ch], u);
                }
            }
    }

    cg::this_grid().sync();   // all stats final; release/acquire at device scope

    // ---- BN affine (one channel per thread, waves 0-3), exact integer stats ----
    if (tid < 256) {
        const int o = tid;
        int s = 0, q = 0;
        #pragma unroll
        for (int rr = 0; rr < NREP; ++rr) {
            s += __hip_atomic_load(&stats[rr * 512 + o],       __ATOMIC_RELAXED, __HIP_MEMORY_SCOPE_AGENT);
            q += __hip_atomic_load(&stats[rr * 512 + 256 + o], __ATOMIC_RELAXED, __HIP_MEMORY_SCOPE_AGENT);
        }
        float scale_w = reduce_partials(partials, o) / 7.0f;
        float t = scale_w / 15.0f;                 // ref: scale_w / qmax_a in f32
        double Cs = 1792.0 * (double)t;            // acc = s * Cs
        const double N = 65536.0;
        double mean_s = (double)s / N;
        double var_s  = (double)q / N - mean_s * mean_s;
        double var    = Cs * Cs * var_s;
        double inv    = 1.0 / sqrt(var + 1e-5);
        double A = Cs * inv * (double)gamma[o];
        double B = (double)beta[o] - Cs * mean_s * inv * (double)gamma[o];
        abA[o] = (float)A;
        abB[o] = (float)B;
    }
    __syncthreads();

    // ---- epilogue from registers: float4 per (t,ot), 64B clusters per row ----
    const float inv15 = 0.066666666666666666f;
    #pragma unroll
    for (int t = 0; t < 16; ++t)
        #pragma unroll
        for (int ot = 0; ot < 2; ++ot) {
            unsigned pk = spack[t * 2 + ot];
            const int ch0 = obase + ot * 16 + quad * 4;
            v4f A4 = *(const v4f*)&abA[ch0];     // 4-lane broadcast reads, conflict-free
            v4f B4 = *(const v4f*)&abB[ch0];
            v4f o4;
            #pragma unroll
            for (int e = 0; e < 4; ++e) {
                float v = (float)((int)(pk << (24 - 8 * e)) >> 24);
                o4[e] = rintf(fminf(fmaxf(v * A4[e] + B4[e], 0.f), 1.f) * 15.f) * inv15;
            }
            const size_t grow = rb0 + (size_t)t * 16 + lr;
            __builtin_nontemporal_store(o4, (v4f*)out + grow * 64 + (ch0 >> 2));
        }
}

// =================== fallback path (old proven 2-kernel pipeline) ===================
template <typename ST>
__global__ __launch_bounds__(512, 4) void k_gemm(
    const float* __restrict__ x, const signed char* __restrict__ wq,
    ST* __restrict__ sbuf, int* __restrict__ stats)
{
    __shared__ __align__(16) signed char ldsx[64 * 272];
    const int tid  = threadIdx.x;
    const int lane = tid & 63;
    const int wv   = tid >> 6;
    const int obase = wv * 32;
    const int lr = lane & 15, quad = lane >> 4;
    const size_t rb0 = (size_t)blockIdx.x * 64;

    v4f f[8];
    const v4f* xb = (const v4f*)(x + rb0 * 256);
    #pragma unroll
    for (int j = 0; j < 8; ++j)
        f[j] = xb[j * 512 + tid];

    v4i wf[2][4];
    #pragma unroll
    for (int ot = 0; ot < 2; ++ot)
        #pragma unroll
        for (int kt = 0; kt < 4; ++kt)
            wf[ot][kt] = *(const v4i*)(wq + (size_t)(obase + ot * 16 + lr) * 256 + kt * 64 + quad * 16);

    #pragma unroll
    for (int j = 0; j < 8; ++j) {
        int idx = j * 512 + tid;
        int row = idx >> 6, c = idx & 63;
        int b0 = (int)rintf(fminf(fmaxf(f[j][0], 0.f), 1.f) * 15.f);
        int b1 = (int)rintf(fminf(fmaxf(f[j][1], 0.f), 1.f) * 15.f);
        int b2 = (int)rintf(fminf(fmaxf(f[j][2], 0.f), 1.f) * 15.f);
        int b3 = (int)rintf(fminf(fmaxf(f[j][3], 0.f), 1.f) * 15.f);
        *(int*)(ldsx + row * 272 + c * 4) = b0 | (b1 << 8) | (b2 << 16) | (b3 << 24);
    }
    __syncthreads();

    int ssum[2] = {0, 0};
    int ssq[2]  = {0, 0};

    #pragma unroll
    for (int t = 0; t < 4; ++t) {
        v4i a[4];
        #pragma unroll
        for (int kt = 0; kt < 4; ++kt)
            a[kt] = *(const v4i*)(ldsx + (t * 16 + lr) * 272 + kt * 64 + quad * 16);
        #pragma unroll
        for (int ot = 0; ot < 2; ++ot) {
            v4i acc0 = {0, 0, 0, 0}, acc1 = {0, 0, 0, 0};
            acc0 = __builtin_amdgcn_mfma_i32_16x16x64_i8(a[0], wf[ot][0], acc0, 0, 0, 0);
            acc0 = __builtin_amdgcn_mfma_i32_16x16x64_i8(a[1], wf[ot][1], acc0, 0, 0, 0);
            acc1 = __builtin_amdgcn_mfma_i32_16x16x64_i8(a[2], wf[ot][2], acc1, 0, 0, 0);
            acc1 = __builtin_amdgcn_mfma_i32_16x16x64_i8(a[3], wf[ot][3], acc1, 0, 0, 0);
            const int ocol = obase + ot * 16 + lr;
            if constexpr (sizeof(ST) == 1) {
                unsigned pack = 0;
                #pragma unroll
                for (int e = 0; e < 4; ++e) {
                    int s = rhe1792(acc0[e]) + rhe1792(acc1[e]);
                    ssum[ot] += s;
                    ssq[ot]  += s * s;
                    pack |= (unsigned)(s & 255) << (8 * e);
                }
                const size_t rg = (size_t)blockIdx.x * 16 + t * 4 + quad;
                ((unsigned*)sbuf)[rg * 256 + ocol] = pack;
            } else {
                ST* sp = sbuf + (rb0 + (size_t)t * 16 + quad * 4) * 256 + ocol;
                #pragma unroll
                for (int e = 0; e < 4; ++e) {
                    int s = rhe1792(acc0[e]) + rhe1792(acc1[e]);
                    ssum[ot] += s;
                    ssq[ot]  += s * s;
                    sp[(size_t)e * 256] = (ST)s;
                }
            }
        }
    }
    int* st = stats + (blockIdx.x & (NREP - 1)) * 512;
    #pragma unroll
    for (int ot = 0; ot < 2; ++ot) {
        int v = ssum[ot], u = ssq[ot];
        v += __shfl_xor(v, 16, 64); v += __shfl_xor(v, 32, 64);
        u += __shfl_xor(u, 16, 64); u += __shfl_xor(u, 32, 64);
        if (quad == 0) {
            atomicAdd(&st[obase + ot * 16 + lr], v);
            atomicAdd(&st[256 + obase + ot * 16 + lr], u);
        }
    }
}

template <typename LT>
__global__ __launch_bounds__(256) void k_out(const LT* sbuf, const int* __restrict__ stats,
                                             const float* __restrict__ partials,
                                             const float* __restrict__ gamma,
                                             const float* __restrict__ beta,
                                             float* out)
{
    __shared__ float2 ab[256];
    const int tid = threadIdx.x;
    {
        int o = tid;
        int s = 0, q = 0;
        #pragma unroll
        for (int rr = 0; rr < NREP; ++rr) {
            s += stats[rr * 512 + o];
            q += stats[rr * 512 + 256 + o];
        }
        float scale_w = reduce_partials(partials, o) / 7.0f;
        float t = scale_w / 15.0f;
        double Cs = 1792.0 * (double)t;
        const double N = 65536.0;
        double mean_s = (double)s / N;
        double var_s  = (double)q / N - mean_s * mean_s;
        double var    = Cs * Cs * var_s;
        double inv    = 1.0 / sqrt(var + 1e-5);
        double A = Cs * inv * (double)gamma[o];
        double B = (double)beta[o] - Cs * mean_s * inv * (double)gamma[o];
        ab[o] = make_float2((float)A, (float)B);
    }
    __syncthreads();

    const int b = blockIdx.x;
    const int d = ((b & 7) << 2) | ((b >> 3) & 3) | (b & ~31);
    const int ci = tid & 63;
    const int c0 = ci * 4;
    const float2 p0 = ab[c0], p1 = ab[c0 + 1], p2 = ab[c0 + 2], p3 = ab[c0 + 3];
    const float inv15 = 0.066666666666666666f;

    if constexpr (sizeof(LT) == 1) {
        const int rg = d * 4 + (tid >> 6);
        v4i V = ((const v4i*)sbuf)[(size_t)rg * 64 + ci];
        #pragma unroll
        for (int j = 0; j < 4; ++j) {
            float v0 = (float)((V[0] << (24 - 8 * j)) >> 24);
            float v1 = (float)((V[1] << (24 - 8 * j)) >> 24);
            float v2 = (float)((V[2] << (24 - 8 * j)) >> 24);
            float v3 = (float)((V[3] << (24 - 8 * j)) >> 24);
            float y0 = rintf(fminf(fmaxf(v0 * p0.x + p0.y, 0.f), 1.f) * 15.f);
            float y1 = rintf(fminf(fmaxf(v1 * p1.x + p1.y, 0.f), 1.f) * 15.f);
            float y2 = rintf(fminf(fmaxf(v2 * p2.x + p2.y, 0.f), 1.f) * 15.f);
            float y3 = rintf(fminf(fmaxf(v3 * p3.x + p3.y, 0.f), 1.f) * 15.f);
            v4f o = { y0 * inv15, y1 * inv15, y2 * inv15, y3 * inv15 };
            __builtin_nontemporal_store(o, (v4f*)out + (size_t)(4 * rg + j) * 64 + ci);
        }
    } else {
        const size_t base = (size_t)d * 1024 + tid;
        #pragma unroll
        for (int j = 0; j < 4; ++j) {
            const size_t F4 = base + (size_t)j * 256;
            v4f fl = ((const v4f*)sbuf)[F4];
            const int oo = (tid * 4) & 255;
            float2 q0 = ab[oo], q1 = ab[oo + 1], q2 = ab[oo + 2], q3 = ab[oo + 3];
            float y0 = rintf(fminf(fmaxf(fl[0] * q0.x + q0.y, 0.f), 1.f) * 15.f);
            float y1 = rintf(fminf(fmaxf(fl[1] * q1.x + q1.y, 0.f), 1.f) * 15.f);
            float y2 = rintf(fminf(fmaxf(fl[2] * q2.x + q2.y, 0.f), 1.f) * 15.f);
            float y3 = rintf(fminf(fmaxf(fl[3] * q3.x + q3.y, 0.f), 1.f) * 15.f);
            v4f o = { y0 * inv15, y1 * inv15, y2 * inv15, y3 * inv15 };
            __builtin_nontemporal_store(o, (v4f*)out + F4);
        }
    }
}

// ---------------- launch ----------------
extern "C" void kernel_launch(void* const* d_in, const int* in_sizes, int n_in,
                              void* d_out, int out_size, void* d_ws, size_t ws_size,
                              hipStream_t stream)
{
    const float* x     = (const float*)d_in[0];
    const float* w     = (const float*)d_in[1];
    const float* gamma = (const float*)d_in[2];
    const float* beta  = (const float*)d_in[3];
    float* out = (float*)d_out;
    char* ws = (char*)d_ws;

    signed char* wq       = (signed char*)(ws + WQ_OFF);
    int*         stats    = (int*)(ws + STATS_OFF);
    float*       partials = (float*)(ws + PART_OFF);

    k_maxabs<<<dim3(64), dim3(256), 0, stream>>>(w, partials, stats);
    k_wquant<<<dim3(64), dim3(256), 0, stream>>>(w, partials, wq);

    hipError_t err = hipErrorUnknown;
    if (ws_size >= WS_MIN) {
        void* kargs[] = { (void*)&x, (void*)&wq, (void*)&partials, (void*)&stats,
                          (void*)&gamma, (void*)&beta, (void*)&out };
        err = hipLaunchCooperativeKernel((const void*)k_fused, dim3(256), dim3(512),
                                         kargs, 0, stream);
    }
    if (err != hipSuccess) {
        // fallback: old proven 4-kernel pipeline
        if (ws_size >= WS_SBUF_NEEDED) {
            signed char* sbuf = (signed char*)(ws + SBUF_OFF);
            k_gemm<signed char><<<dim3(1024), dim3(512), 0, stream>>>(x, wq, sbuf, stats);
            k_out<signed char><<<dim3(4096), dim3(256), 0, stream>>>(sbuf, stats, partials,
                                                                     gamma, beta, out);
        } else {
            k_gemm<float><<<dim3(1024), dim3(512), 0, stream>>>(x, wq, out, stats);
            k_out<float><<<dim3(4096), dim3(256), 0, stream>>>(out, stats, partials,
                                                               gamma, beta, out);
        }
    }
}

// Round 5
// 179.206 us; speedup vs baseline: 1.3302x; 1.1252x over previous
//
#include <hip/hip_runtime.h>
#include <hip/hip_cooperative_groups.h>
#include <cstdint>
#include <cstddef>

namespace cg = cooperative_groups;

typedef int   v4i __attribute__((ext_vector_type(4)));
typedef float v4f __attribute__((ext_vector_type(4)));

static constexpr int NREP = 8;    // stats replica count (atomic contention spreading)

// ---------------- workspace layout (bytes) ----------------
static constexpr size_t WQ_OFF    = 0;                        // 65536 int8 weights
static constexpr size_t STATS_OFF = 65536;                    // NREP*512 int32 = 16384
static constexpr size_t PART_OFF  = STATS_OFF + NREP*512*4;   // 64 floats
static constexpr size_t SBUF_OFF  = 131072 + 2048;            // 16 MiB s-values (fallback path)
static constexpr size_t WS_SBUF_NEEDED = SBUF_OFF + (size_t)65536 * 256;
static constexpr size_t WS_MIN    = PART_OFF + 64 * 4;        // cooperative path needs only this

// exact round-half-even of p/1792 for |p| <= 13440 (1792 = 7*256)
__device__ __forceinline__ int rhe1792(int p) {
    unsigned u = (unsigned)(p + 17024);      // (p+896) + 9*1792, u in [3584,30464]
    unsigned v = u >> 8;                     // floor(u/256), in [14,119]
    unsigned d = (v * 147u) >> 10;           // floor(v/7), exact for v<=119
    int q = (int)d - 9;                      // round-half-up(p/1792)
    unsigned tie = (unsigned)(((u & 255u) | (v - 7u * d)) == 0u);
    q -= (int)(tie & ((unsigned)q & 1u));    // half-even: ties round to even
    return q;
}

// ---------------- k1: per-block max|w| partials + zero stats ----------------
__global__ void k_maxabs(const float* __restrict__ w, float* __restrict__ partials,
                         int* __restrict__ stats) {
    __shared__ float wmax[4];
    int idx = blockIdx.x * 256 + threadIdx.x;     // 64 blocks * 256 = 16384 float4
    float4 f = ((const float4*)w)[idx];
    float m = fmaxf(fmaxf(fabsf(f.x), fabsf(f.y)), fmaxf(fabsf(f.z), fabsf(f.w)));
    #pragma unroll
    for (int s = 32; s > 0; s >>= 1) m = fmaxf(m, __shfl_xor(m, s, 64));
    if ((threadIdx.x & 63) == 0) wmax[threadIdx.x >> 6] = m;
    if (idx < NREP * 512) stats[idx] = 0;         // zero replicas
    __syncthreads();
    if (threadIdx.x == 0)
        partials[blockIdx.x] = fmaxf(fmaxf(wmax[0], wmax[1]), fmaxf(wmax[2], wmax[3]));
}

// wave-redundant reduce of the 64 partials (L2-hot) -> global max|w|
__device__ __forceinline__ float reduce_partials(const float* __restrict__ partials, int tid) {
    float p = partials[tid & 63];
    #pragma unroll
    for (int s = 32; s > 0; s >>= 1) p = fmaxf(p, __shfl_xor(p, s, 64));
    return p;
}

// ---------------- k2: quantize weights to int8 ----------------
__global__ void k_wquant(const float* __restrict__ w, const float* __restrict__ partials,
                         signed char* __restrict__ wq) {
    int idx = blockIdx.x * 256 + threadIdx.x;
    float scale = reduce_partials(partials, threadIdx.x) / 7.0f;  // scale_w (f32 div, as ref)
    float4 f = ((const float4*)w)[idx];
    int q0 = (int)rintf(fminf(fmaxf(f.x / scale, -7.f), 7.f));
    int q1 = (int)rintf(fminf(fmaxf(f.y / scale, -7.f), 7.f));
    int q2 = (int)rintf(fminf(fmaxf(f.z / scale, -7.f), 7.f));
    int q3 = (int)rintf(fminf(fmaxf(f.w / scale, -7.f), 7.f));
    ((int*)wq)[idx] = (q0 & 255) | ((q1 & 255) << 8) | ((q2 & 255) << 16) | ((q3 & 255) << 24);
}

// ---------------- k3 (cooperative): GEMM + stats, grid.sync, BN + output ----
// 256 blocks x 512 threads (8 waves), 256 batch rows/block. s values live in a
// conflict-free LDS buffer across the grid sync (rounds 1/3/4 lesson: the
// compiler pins VGPR at <=128 for this kernel regardless of launch bounds, so
// keeping 32 persistent dwords/thread in registers spilled ~43 MB to scratch;
// WRITE_SIZE 110 MB vs 67 MB output was the smoking gun). With spack in LDS
// the persistent demand is ~90 VGPR -> no spill by construction.
// LDS: ldsx 69.6KB + slds 64KB + ab 2KB = 134KB < 160KB at 1 block/CU.
// MFMA operands swapped (A=weights, B=acts): C row = channel (quad*4+e),
// col = batch row (lr) -> phase-2 writes are float4 / 64B clusters.
__global__ __launch_bounds__(512, 1) void k_fused(
    const float* __restrict__ x, const signed char* __restrict__ wq,
    const float* __restrict__ partials, int* __restrict__ stats,
    const float* __restrict__ gamma, const float* __restrict__ beta,
    float* __restrict__ out)
{
    __shared__ __align__(16) signed char ldsx[256 * 272];  // 256 rows x 256 k (+16B pad/row)
    __shared__ __align__(16) unsigned slds[32 * 512];      // s-packs: [t*2+ot][tid], 64 KB
    __shared__ __align__(16) float abA[256];
    __shared__ __align__(16) float abB[256];

    const int tid  = threadIdx.x;
    const int lane = tid & 63;
    const int wv   = tid >> 6;            // 0..7
    const int obase = wv * 32;            // 32 channels per wave
    const int lr = lane & 15, quad = lane >> 4;
    const size_t rb0 = (size_t)blockIdx.x * 256;

    // ---- weight fragments (L2-hot): A row = channel, k = kt*64 + quad*16 + i ----
    v4i wf[2][4];
    #pragma unroll
    for (int ot = 0; ot < 2; ++ot)
        #pragma unroll
        for (int kt = 0; kt < 4; ++kt)
            wf[ot][kt] = *(const v4i*)(wq + (size_t)(obase + ot * 16 + lr) * 256 + kt * 64 + quad * 16);

    // ---- stage x -> quantize -> LDS, 4 passes of 8 float4/thread (256 rows) ----
    const v4f* xb = (const v4f*)(x + rb0 * 256);
    #pragma unroll
    for (int p = 0; p < 4; ++p) {
        v4f f[8];
        #pragma unroll
        for (int j = 0; j < 8; ++j)
            f[j] = xb[p * 4096 + j * 512 + tid];
        #pragma unroll
        for (int j = 0; j < 8; ++j) {
            int idx = p * 4096 + j * 512 + tid;   // float4 flat index (0..16383)
            int row = idx >> 6, c = idx & 63;     // 64 float4 per row
            int b0 = (int)rintf(fminf(fmaxf(f[j][0], 0.f), 1.f) * 15.f);
            int b1 = (int)rintf(fminf(fmaxf(f[j][1], 0.f), 1.f) * 15.f);
            int b2 = (int)rintf(fminf(fmaxf(f[j][2], 0.f), 1.f) * 15.f);
            int b3 = (int)rintf(fminf(fmaxf(f[j][3], 0.f), 1.f) * 15.f);
            *(int*)(ldsx + row * 272 + c * 4) = b0 | (b1 << 8) | (b2 << 16) | (b3 << 24);
        }
    }
    __syncthreads();   // the ONLY block barrier in phase 1

    int ssum[2][4] = {};
    int ssq [2][4] = {};

    #pragma unroll
    for (int t = 0; t < 16; ++t) {
        v4i a[4];
        #pragma unroll
        for (int kt = 0; kt < 4; ++kt)
            a[kt] = *(const v4i*)(ldsx + (t * 16 + lr) * 272 + kt * 64 + quad * 16);
        #pragma unroll
        for (int ot = 0; ot < 2; ++ot) {
            v4i acc0 = {0, 0, 0, 0}, acc1 = {0, 0, 0, 0};
            // D[r=channel][c=batchrow]: A = weights, B = acts (swapped)
            acc0 = __builtin_amdgcn_mfma_i32_16x16x64_i8(wf[ot][0], a[0], acc0, 0, 0, 0);
            acc0 = __builtin_amdgcn_mfma_i32_16x16x64_i8(wf[ot][1], a[1], acc0, 0, 0, 0);
            acc1 = __builtin_amdgcn_mfma_i32_16x16x64_i8(wf[ot][2], a[2], acc1, 0, 0, 0);
            acc1 = __builtin_amdgcn_mfma_i32_16x16x64_i8(wf[ot][3], a[3], acc1, 0, 0, 0);
            unsigned pack = 0;
            #pragma unroll
            for (int e = 0; e < 4; ++e) {
                int s = rhe1792(acc0[e]) + rhe1792(acc1[e]);   // exact, in [-16,16]
                ssum[ot][e] += s;
                ssq [ot][e] += s * s;
                pack |= (unsigned)(s & 255) << (8 * e);
            }
            // conflict-free: consecutive tid -> consecutive dwords; own-thread
            // readback in phase 2 (no barrier needed, LDS persists grid.sync)
            slds[(t * 2 + ot) * 512 + tid] = pack;
        }
    }

    // ---- per-channel stats: reduce across the 16 lr-lanes, atomics to replicas ----
    {
        int* st = stats + (blockIdx.x & (NREP - 1)) * 512;
        #pragma unroll
        for (int ot = 0; ot < 2; ++ot)
            #pragma unroll
            for (int e = 0; e < 4; ++e) {
                int v = ssum[ot][e], u = ssq[ot][e];
                v += __shfl_xor(v, 1, 64); v += __shfl_xor(v, 2, 64);
                v += __shfl_xor(v, 4, 64); v += __shfl_xor(v, 8, 64);
                u += __shfl_xor(u, 1, 64); u += __shfl_xor(u, 2, 64);
                u += __shfl_xor(u, 4, 64); u += __shfl_xor(u, 8, 64);
                if (lr == 0) {
                    int ch = obase + ot * 16 + quad * 4 + e;
                    atomicAdd(&st[ch], v);
                    atomicAdd(&st[256 + ch], u);
                }
            }
    }

    cg::this_grid().sync();   // all stats final; release/acquire at device scope

    // ---- BN affine (one channel per thread, waves 0-3), exact integer stats ----
    if (tid < 256) {
        const int o = tid;
        int s = 0, q = 0;
        #pragma unroll
        for (int rr = 0; rr < NREP; ++rr) {
            s += __hip_atomic_load(&stats[rr * 512 + o],       __ATOMIC_RELAXED, __HIP_MEMORY_SCOPE_AGENT);
            q += __hip_atomic_load(&stats[rr * 512 + 256 + o], __ATOMIC_RELAXED, __HIP_MEMORY_SCOPE_AGENT);
        }
        float scale_w = reduce_partials(partials, o) / 7.0f;
        float t = scale_w / 15.0f;                 // ref: scale_w / qmax_a in f32
        double Cs = 1792.0 * (double)t;            // acc = s * Cs
        const double N = 65536.0;
        double mean_s = (double)s / N;
        double var_s  = (double)q / N - mean_s * mean_s;
        double var    = Cs * Cs * var_s;
        double inv    = 1.0 / sqrt(var + 1e-5);
        double A = Cs * inv * (double)gamma[o];
        double B = (double)beta[o] - Cs * mean_s * inv * (double)gamma[o];
        abA[o] = (float)A;
        abB[o] = (float)B;
    }
    __syncthreads();

    // ---- epilogue from slds: float4 per (t,ot), 64B clusters per row ----
    const float inv15 = 0.066666666666666666f;
    #pragma unroll
    for (int ot = 0; ot < 2; ++ot) {
        const int ch0 = obase + ot * 16 + quad * 4;
        v4f A4 = *(const v4f*)&abA[ch0];     // loop-invariant, hoisted (broadcast reads)
        v4f B4 = *(const v4f*)&abB[ch0];
        #pragma unroll
        for (int t = 0; t < 16; ++t) {
            unsigned pk = slds[(t * 2 + ot) * 512 + tid];
            v4f o4;
            #pragma unroll
            for (int e = 0; e < 4; ++e) {
                float v = (float)((int)(pk << (24 - 8 * e)) >> 24);
                o4[e] = rintf(fminf(fmaxf(v * A4[e] + B4[e], 0.f), 1.f) * 15.f) * inv15;
            }
            const size_t grow = rb0 + (size_t)t * 16 + lr;
            __builtin_nontemporal_store(o4, (v4f*)out + grow * 64 + (ch0 >> 2));
        }
    }
}

// =================== fallback path (old proven 2-kernel pipeline) ===================
template <typename ST>
__global__ __launch_bounds__(512, 4) void k_gemm(
    const float* __restrict__ x, const signed char* __restrict__ wq,
    ST* __restrict__ sbuf, int* __restrict__ stats)
{
    __shared__ __align__(16) signed char ldsx[64 * 272];
    const int tid  = threadIdx.x;
    const int lane = tid & 63;
    const int wv   = tid >> 6;
    const int obase = wv * 32;
    const int lr = lane & 15, quad = lane >> 4;
    const size_t rb0 = (size_t)blockIdx.x * 64;

    v4f f[8];
    const v4f* xb = (const v4f*)(x + rb0 * 256);
    #pragma unroll
    for (int j = 0; j < 8; ++j)
        f[j] = xb[j * 512 + tid];

    v4i wf[2][4];
    #pragma unroll
    for (int ot = 0; ot < 2; ++ot)
        #pragma unroll
        for (int kt = 0; kt < 4; ++kt)
            wf[ot][kt] = *(const v4i*)(wq + (size_t)(obase + ot * 16 + lr) * 256 + kt * 64 + quad * 16);

    #pragma unroll
    for (int j = 0; j < 8; ++j) {
        int idx = j * 512 + tid;
        int row = idx >> 6, c = idx & 63;
        int b0 = (int)rintf(fminf(fmaxf(f[j][0], 0.f), 1.f) * 15.f);
        int b1 = (int)rintf(fminf(fmaxf(f[j][1], 0.f), 1.f) * 15.f);
        int b2 = (int)rintf(fminf(fmaxf(f[j][2], 0.f), 1.f) * 15.f);
        int b3 = (int)rintf(fminf(fmaxf(f[j][3], 0.f), 1.f) * 15.f);
        *(int*)(ldsx + row * 272 + c * 4) = b0 | (b1 << 8) | (b2 << 16) | (b3 << 24);
    }
    __syncthreads();

    int ssum[2] = {0, 0};
    int ssq[2]  = {0, 0};

    #pragma unroll
    for (int t = 0; t < 4; ++t) {
        v4i a[4];
        #pragma unroll
        for (int kt = 0; kt < 4; ++kt)
            a[kt] = *(const v4i*)(ldsx + (t * 16 + lr) * 272 + kt * 64 + quad * 16);
        #pragma unroll
        for (int ot = 0; ot < 2; ++ot) {
            v4i acc0 = {0, 0, 0, 0}, acc1 = {0, 0, 0, 0};
            acc0 = __builtin_amdgcn_mfma_i32_16x16x64_i8(a[0], wf[ot][0], acc0, 0, 0, 0);
            acc0 = __builtin_amdgcn_mfma_i32_16x16x64_i8(a[1], wf[ot][1], acc0, 0, 0, 0);
            acc1 = __builtin_amdgcn_mfma_i32_16x16x64_i8(a[2], wf[ot][2], acc1, 0, 0, 0);
            acc1 = __builtin_amdgcn_mfma_i32_16x16x64_i8(a[3], wf[ot][3], acc1, 0, 0, 0);
            const int ocol = obase + ot * 16 + lr;
            if constexpr (sizeof(ST) == 1) {
                unsigned pack = 0;
                #pragma unroll
                for (int e = 0; e < 4; ++e) {
                    int s = rhe1792(acc0[e]) + rhe1792(acc1[e]);
                    ssum[ot] += s;
                    ssq[ot]  += s * s;
                    pack |= (unsigned)(s & 255) << (8 * e);
                }
                const size_t rg = (size_t)blockIdx.x * 16 + t * 4 + quad;
                ((unsigned*)sbuf)[rg * 256 + ocol] = pack;
            } else {
                ST* sp = sbuf + (rb0 + (size_t)t * 16 + quad * 4) * 256 + ocol;
                #pragma unroll
                for (int e = 0; e < 4; ++e) {
                    int s = rhe1792(acc0[e]) + rhe1792(acc1[e]);
                    ssum[ot] += s;
                    ssq[ot]  += s * s;
                    sp[(size_t)e * 256] = (ST)s;
                }
            }
        }
    }
    int* st = stats + (blockIdx.x & (NREP - 1)) * 512;
    #pragma unroll
    for (int ot = 0; ot < 2; ++ot) {
        int v = ssum[ot], u = ssq[ot];
        v += __shfl_xor(v, 16, 64); v += __shfl_xor(v, 32, 64);
        u += __shfl_xor(u, 16, 64); u += __shfl_xor(u, 32, 64);
        if (quad == 0) {
            atomicAdd(&st[obase + ot * 16 + lr], v);
            atomicAdd(&st[256 + obase + ot * 16 + lr], u);
        }
    }
}

template <typename LT>
__global__ __launch_bounds__(256) void k_out(const LT* sbuf, const int* __restrict__ stats,
                                             const float* __restrict__ partials,
                                             const float* __restrict__ gamma,
                                             const float* __restrict__ beta,
                                             float* out)
{
    __shared__ float2 ab[256];
    const int tid = threadIdx.x;
    {
        int o = tid;
        int s = 0, q = 0;
        #pragma unroll
        for (int rr = 0; rr < NREP; ++rr) {
            s += stats[rr * 512 + o];
            q += stats[rr * 512 + 256 + o];
        }
        float scale_w = reduce_partials(partials, o) / 7.0f;
        float t = scale_w / 15.0f;
        double Cs = 1792.0 * (double)t;
        const double N = 65536.0;
        double mean_s = (double)s / N;
        double var_s  = (double)q / N - mean_s * mean_s;
        double var    = Cs * Cs * var_s;
        double inv    = 1.0 / sqrt(var + 1e-5);
        double A = Cs * inv * (double)gamma[o];
        double B = (double)beta[o] - Cs * mean_s * inv * (double)gamma[o];
        ab[o] = make_float2((float)A, (float)B);
    }
    __syncthreads();

    const int b = blockIdx.x;
    const int d = ((b & 7) << 2) | ((b >> 3) & 3) | (b & ~31);
    const int ci = tid & 63;
    const int c0 = ci * 4;
    const float2 p0 = ab[c0], p1 = ab[c0 + 1], p2 = ab[c0 + 2], p3 = ab[c0 + 3];
    const float inv15 = 0.066666666666666666f;

    if constexpr (sizeof(LT) == 1) {
        const int rg = d * 4 + (tid >> 6);
        v4i V = ((const v4i*)sbuf)[(size_t)rg * 64 + ci];
        #pragma unroll
        for (int j = 0; j < 4; ++j) {
            float v0 = (float)((V[0] << (24 - 8 * j)) >> 24);
            float v1 = (float)((V[1] << (24 - 8 * j)) >> 24);
            float v2 = (float)((V[2] << (24 - 8 * j)) >> 24);
            float v3 = (float)((V[3] << (24 - 8 * j)) >> 24);
            float y0 = rintf(fminf(fmaxf(v0 * p0.x + p0.y, 0.f), 1.f) * 15.f);
            float y1 = rintf(fminf(fmaxf(v1 * p1.x + p1.y, 0.f), 1.f) * 15.f);
            float y2 = rintf(fminf(fmaxf(v2 * p2.x + p2.y, 0.f), 1.f) * 15.f);
            float y3 = rintf(fminf(fmaxf(v3 * p3.x + p3.y, 0.f), 1.f) * 15.f);
            v4f o = { y0 * inv15, y1 * inv15, y2 * inv15, y3 * inv15 };
            __builtin_nontemporal_store(o, (v4f*)out + (size_t)(4 * rg + j) * 64 + ci);
        }
    } else {
        const size_t base = (size_t)d * 1024 + tid;
        #pragma unroll
        for (int j = 0; j < 4; ++j) {
            const size_t F4 = base + (size_t)j * 256;
            v4f fl = ((const v4f*)sbuf)[F4];
            const int oo = (tid * 4) & 255;
            float2 q0 = ab[oo], q1 = ab[oo + 1], q2 = ab[oo + 2], q3 = ab[oo + 3];
            float y0 = rintf(fminf(fmaxf(fl[0] * q0.x + q0.y, 0.f), 1.f) * 15.f);
            float y1 = rintf(fminf(fmaxf(fl[1] * q1.x + q1.y, 0.f), 1.f) * 15.f);
            float y2 = rintf(fminf(fmaxf(fl[2] * q2.x + q2.y, 0.f), 1.f) * 15.f);
            float y3 = rintf(fminf(fmaxf(fl[3] * q3.x + q3.y, 0.f), 1.f) * 15.f);
            v4f o = { y0 * inv15, y1 * inv15, y2 * inv15, y3 * inv15 };
            __builtin_nontemporal_store(o, (v4f*)out + F4);
        }
    }
}

// ---------------- launch ----------------
extern "C" void kernel_launch(void* const* d_in, const int* in_sizes, int n_in,
                              void* d_out, int out_size, void* d_ws, size_t ws_size,
                              hipStream_t stream)
{
    const float* x     = (const float*)d_in[0];
    const float* w     = (const float*)d_in[1];
    const float* gamma = (const float*)d_in[2];
    const float* beta  = (const float*)d_in[3];
    float* out = (float*)d_out;
    char* ws = (char*)d_ws;

    signed char* wq       = (signed char*)(ws + WQ_OFF);
    int*         stats    = (int*)(ws + STATS_OFF);
    float*       partials = (float*)(ws + PART_OFF);

    k_maxabs<<<dim3(64), dim3(256), 0, stream>>>(w, partials, stats);
    k_wquant<<<dim3(64), dim3(256), 0, stream>>>(w, partials, wq);

    hipError_t err = hipErrorUnknown;
    if (ws_size >= WS_MIN) {
        void* kargs[] = { (void*)&x, (void*)&wq, (void*)&partials, (void*)&stats,
                          (void*)&gamma, (void*)&beta, (void*)&out };
        err = hipLaunchCooperativeKernel((const void*)k_fused, dim3(256), dim3(512),
                                         kargs, 0, stream);
    }
    if (err != hipSuccess) {
        // fallback: old proven 4-kernel pipeline
        if (ws_size >= WS_SBUF_NEEDED) {
            signed char* sbuf = (signed char*)(ws + SBUF_OFF);
            k_gemm<signed char><<<dim3(1024), dim3(512), 0, stream>>>(x, wq, sbuf, stats);
            k_out<signed char><<<dim3(4096), dim3(256), 0, stream>>>(sbuf, stats, partials,
                                                                     gamma, beta, out);
        } else {
            k_gemm<float><<<dim3(1024), dim3(512), 0, stream>>>(x, wq, out, stats);
            k_out<float><<<dim3(4096), dim3(256), 0, stream>>>(out, stats, partials,
                                                               gamma, beta, out);
        }
    }
}

// Round 6
// 155.395 us; speedup vs baseline: 1.5341x; 1.1532x over previous
//
#include <hip/hip_runtime.h>
#include <cstdint>
#include <cstddef>

typedef int   v4i __attribute__((ext_vector_type(4)));
typedef float v4f __attribute__((ext_vector_type(4)));

static constexpr int NREP = 8;    // stats replica count (atomic contention spreading)

// ---------------- workspace layout (bytes) ----------------
static constexpr size_t WQ_OFF    = 0;                        // 65536 int8 weights
static constexpr size_t STATS_OFF = 65536;                    // NREP*512 int32 = 16384
static constexpr size_t PART_OFF  = STATS_OFF + NREP*512*4;   // 64 floats
static constexpr size_t BAR_OFF   = PART_OFF + 64*4;          // 1 int (grid barrier)
static constexpr size_t SBUF_OFF  = 131072 + 2048;            // 16 MiB s-values (fallback path)
static constexpr size_t WS_SBUF_NEEDED = SBUF_OFF + (size_t)65536 * 256;
static constexpr size_t WS_MIN    = BAR_OFF + 64;             // fused path needs only this

// exact round-half-even of p/1792 for |p| <= 13440 (1792 = 7*256)
__device__ __forceinline__ int rhe1792(int p) {
    unsigned u = (unsigned)(p + 17024);      // (p+896) + 9*1792, u in [3584,30464]
    unsigned v = u >> 8;                     // floor(u/256), in [14,119]
    unsigned d = (v * 147u) >> 10;           // floor(v/7), exact for v<=119
    int q = (int)d - 9;                      // round-half-up(p/1792)
    unsigned tie = (unsigned)(((u & 255u) | (v - 7u * d)) == 0u);
    q -= (int)(tie & ((unsigned)q & 1u));    // half-even: ties round to even
    return q;
}

// ---------------- k1: per-block max|w| partials + zero stats + zero barrier ----
__global__ void k_maxabs(const float* __restrict__ w, float* __restrict__ partials,
                         int* __restrict__ stats, int* __restrict__ bar) {
    __shared__ float wmax[4];
    int idx = blockIdx.x * 256 + threadIdx.x;     // 64 blocks * 256 = 16384 float4
    float4 f = ((const float4*)w)[idx];
    float m = fmaxf(fmaxf(fabsf(f.x), fabsf(f.y)), fmaxf(fabsf(f.z), fabsf(f.w)));
    #pragma unroll
    for (int s = 32; s > 0; s >>= 1) m = fmaxf(m, __shfl_xor(m, s, 64));
    if ((threadIdx.x & 63) == 0) wmax[threadIdx.x >> 6] = m;
    if (idx < NREP * 512) stats[idx] = 0;         // zero replicas
    if (idx == 0) *bar = 0;                       // zero grid barrier (ws is poisoned)
    __syncthreads();
    if (threadIdx.x == 0)
        partials[blockIdx.x] = fmaxf(fmaxf(wmax[0], wmax[1]), fmaxf(wmax[2], wmax[3]));
}

// wave-redundant reduce of the 64 partials (L2-hot) -> global max|w|
__device__ __forceinline__ float reduce_partials(const float* __restrict__ partials, int tid) {
    float p = partials[tid & 63];
    #pragma unroll
    for (int s = 32; s > 0; s >>= 1) p = fmaxf(p, __shfl_xor(p, s, 64));
    return p;
}

// ---------------- k2: quantize weights to int8 ----------------
__global__ void k_wquant(const float* __restrict__ w, const float* __restrict__ partials,
                         signed char* __restrict__ wq) {
    int idx = blockIdx.x * 256 + threadIdx.x;
    float scale = reduce_partials(partials, threadIdx.x) / 7.0f;  // scale_w (f32 div, as ref)
    float4 f = ((const float4*)w)[idx];
    int q0 = (int)rintf(fminf(fmaxf(f.x / scale, -7.f), 7.f));
    int q1 = (int)rintf(fminf(fmaxf(f.y / scale, -7.f), 7.f));
    int q2 = (int)rintf(fminf(fmaxf(f.z / scale, -7.f), 7.f));
    int q3 = (int)rintf(fminf(fmaxf(f.w / scale, -7.f), 7.f));
    ((int*)wq)[idx] = (q0 & 255) | ((q1 & 255) << 8) | ((q2 & 255) << 16) | ((q3 & 255) << 24);
}

// ---------------- k3: fused GEMM + stats, MANUAL grid barrier, BN + output ----
// 256 blocks x 512 threads (8 waves), 256 batch rows/block, REGULAR launch
// (graph-capturable). Rounds 1-5 showed the cooperative path carries ~65us
// fixed per-iteration overhead (total - kernels was ~115us on every coop
// round vs ~10-15us for the round-0 regular pipeline) -> replace grid.sync
// with a spin barrier. Safety: LDS 134KB forces 1 block/CU, grid 256 = CU
// count -> all blocks necessarily co-resident; a bounded spin (~10ms) turns
// any residency anomaly into a wrong answer instead of a hang.
// s-packs live in LDS across the barrier (round-5 fix: compiler pins VGPR at
// <=128 here; register-resident s spilled ~43MB to scratch). VGPR now 88.
// MFMA operands swapped (A=weights, B=acts): C row = channel (quad*4+e),
// col = batch row (lr) -> phase-2 writes are float4 / 64B clusters.
__global__ __launch_bounds__(512, 1) void k_fused(
    const float* __restrict__ x, const signed char* __restrict__ wq,
    const float* __restrict__ partials, int* __restrict__ stats,
    int* __restrict__ bar,
    const float* __restrict__ gamma, const float* __restrict__ beta,
    float* __restrict__ out)
{
    __shared__ __align__(16) signed char ldsx[256 * 272];  // 256 rows x 256 k (+16B pad/row)
    __shared__ __align__(16) unsigned slds[32 * 512];      // s-packs: [t*2+ot][tid], 64 KB
    __shared__ __align__(16) float abA[256];
    __shared__ __align__(16) float abB[256];

    const int tid  = threadIdx.x;
    const int lane = tid & 63;
    const int wv   = tid >> 6;            // 0..7
    const int obase = wv * 32;            // 32 channels per wave
    const int lr = lane & 15, quad = lane >> 4;
    const size_t rb0 = (size_t)blockIdx.x * 256;

    // ---- weight fragments (L2-hot): A row = channel, k = kt*64 + quad*16 + i ----
    v4i wf[2][4];
    #pragma unroll
    for (int ot = 0; ot < 2; ++ot)
        #pragma unroll
        for (int kt = 0; kt < 4; ++kt)
            wf[ot][kt] = *(const v4i*)(wq + (size_t)(obase + ot * 16 + lr) * 256 + kt * 64 + quad * 16);

    // ---- stage x -> quantize -> LDS, 4 passes of 8 float4/thread (256 rows) ----
    const v4f* xb = (const v4f*)(x + rb0 * 256);
    #pragma unroll
    for (int p = 0; p < 4; ++p) {
        v4f f[8];
        #pragma unroll
        for (int j = 0; j < 8; ++j)
            f[j] = xb[p * 4096 + j * 512 + tid];
        #pragma unroll
        for (int j = 0; j < 8; ++j) {
            int idx = p * 4096 + j * 512 + tid;   // float4 flat index (0..16383)
            int row = idx >> 6, c = idx & 63;     // 64 float4 per row
            int b0 = (int)rintf(fminf(fmaxf(f[j][0], 0.f), 1.f) * 15.f);
            int b1 = (int)rintf(fminf(fmaxf(f[j][1], 0.f), 1.f) * 15.f);
            int b2 = (int)rintf(fminf(fmaxf(f[j][2], 0.f), 1.f) * 15.f);
            int b3 = (int)rintf(fminf(fmaxf(f[j][3], 0.f), 1.f) * 15.f);
            *(int*)(ldsx + row * 272 + c * 4) = b0 | (b1 << 8) | (b2 << 16) | (b3 << 24);
        }
    }
    __syncthreads();   // the ONLY block barrier in phase 1

    int ssum[2][4] = {};
    int ssq [2][4] = {};

    #pragma unroll
    for (int t = 0; t < 16; ++t) {
        v4i a[4];
        #pragma unroll
        for (int kt = 0; kt < 4; ++kt)
            a[kt] = *(const v4i*)(ldsx + (t * 16 + lr) * 272 + kt * 64 + quad * 16);
        #pragma unroll
        for (int ot = 0; ot < 2; ++ot) {
            v4i acc0 = {0, 0, 0, 0}, acc1 = {0, 0, 0, 0};
            // D[r=channel][c=batchrow]: A = weights, B = acts (swapped)
            acc0 = __builtin_amdgcn_mfma_i32_16x16x64_i8(wf[ot][0], a[0], acc0, 0, 0, 0);
            acc0 = __builtin_amdgcn_mfma_i32_16x16x64_i8(wf[ot][1], a[1], acc0, 0, 0, 0);
            acc1 = __builtin_amdgcn_mfma_i32_16x16x64_i8(wf[ot][2], a[2], acc1, 0, 0, 0);
            acc1 = __builtin_amdgcn_mfma_i32_16x16x64_i8(wf[ot][3], a[3], acc1, 0, 0, 0);
            unsigned pack = 0;
            #pragma unroll
            for (int e = 0; e < 4; ++e) {
                int s = rhe1792(acc0[e]) + rhe1792(acc1[e]);   // exact, in [-16,16]
                ssum[ot][e] += s;
                ssq [ot][e] += s * s;
                pack |= (unsigned)(s & 255) << (8 * e);
            }
            // conflict-free: consecutive tid -> consecutive dwords; own-thread
            // readback in phase 2 (LDS persists across the grid barrier)
            slds[(t * 2 + ot) * 512 + tid] = pack;
        }
    }

    // ---- per-channel stats: reduce across the 16 lr-lanes, atomics to replicas ----
    {
        int* st = stats + (blockIdx.x & (NREP - 1)) * 512;
        #pragma unroll
        for (int ot = 0; ot < 2; ++ot)
            #pragma unroll
            for (int e = 0; e < 4; ++e) {
                int v = ssum[ot][e], u = ssq[ot][e];
                v += __shfl_xor(v, 1, 64); v += __shfl_xor(v, 2, 64);
                v += __shfl_xor(v, 4, 64); v += __shfl_xor(v, 8, 64);
                u += __shfl_xor(u, 1, 64); u += __shfl_xor(u, 2, 64);
                u += __shfl_xor(u, 4, 64); u += __shfl_xor(u, 8, 64);
                if (lr == 0) {
                    int ch = obase + ot * 16 + quad * 4 + e;
                    atomicAdd(&st[ch], v);
                    atomicAdd(&st[256 + ch], u);
                }
            }
    }

    // ---- manual grid barrier (all 256 blocks co-resident: 1 block/CU, 256 CUs) ----
    __syncthreads();   // drains this block's stats atomics (vmcnt(0) before s_barrier)
    if (tid == 0) {
        __threadfence();                         // release stats before arrival
        atomicAdd(bar, 1);                       // device-scope arrival
        int it = 0;
        while (__hip_atomic_load(bar, __ATOMIC_ACQUIRE, __HIP_MEMORY_SCOPE_AGENT) < 256) {
            __builtin_amdgcn_s_sleep(2);
            if (++it > 200000) break;            // ~10ms safety valve: wrong > hung
        }
    }
    __syncthreads();   // all threads see barrier passed

    // ---- BN affine (one channel per thread, waves 0-3), exact integer stats ----
    if (tid < 256) {
        const int o = tid;
        int s = 0, q = 0;
        #pragma unroll
        for (int rr = 0; rr < NREP; ++rr) {
            s += __hip_atomic_load(&stats[rr * 512 + o],       __ATOMIC_RELAXED, __HIP_MEMORY_SCOPE_AGENT);
            q += __hip_atomic_load(&stats[rr * 512 + 256 + o], __ATOMIC_RELAXED, __HIP_MEMORY_SCOPE_AGENT);
        }
        float scale_w = reduce_partials(partials, o) / 7.0f;
        float t = scale_w / 15.0f;                 // ref: scale_w / qmax_a in f32
        double Cs = 1792.0 * (double)t;            // acc = s * Cs
        const double N = 65536.0;
        double mean_s = (double)s / N;
        double var_s  = (double)q / N - mean_s * mean_s;
        double var    = Cs * Cs * var_s;
        double inv    = 1.0 / sqrt(var + 1e-5);
        double A = Cs * inv * (double)gamma[o];
        double B = (double)beta[o] - Cs * mean_s * inv * (double)gamma[o];
        abA[o] = (float)A;
        abB[o] = (float)B;
    }
    __syncthreads();

    // ---- epilogue from slds: float4 per (t,ot), 64B clusters per row ----
    const float inv15 = 0.066666666666666666f;
    #pragma unroll
    for (int ot = 0; ot < 2; ++ot) {
        const int ch0 = obase + ot * 16 + quad * 4;
        v4f A4 = *(const v4f*)&abA[ch0];     // loop-invariant, hoisted (broadcast reads)
        v4f B4 = *(const v4f*)&abB[ch0];
        #pragma unroll
        for (int t = 0; t < 16; ++t) {
            unsigned pk = slds[(t * 2 + ot) * 512 + tid];
            v4f o4;
            #pragma unroll
            for (int e = 0; e < 4; ++e) {
                float v = (float)((int)(pk << (24 - 8 * e)) >> 24);
                o4[e] = rintf(fminf(fmaxf(v * A4[e] + B4[e], 0.f), 1.f) * 15.f) * inv15;
            }
            const size_t grow = rb0 + (size_t)t * 16 + lr;
            __builtin_nontemporal_store(o4, (v4f*)out + grow * 64 + (ch0 >> 2));
        }
    }
}

// =================== fallback path (old proven 2-kernel pipeline) ===================
template <typename ST>
__global__ __launch_bounds__(512, 4) void k_gemm(
    const float* __restrict__ x, const signed char* __restrict__ wq,
    ST* __restrict__ sbuf, int* __restrict__ stats)
{
    __shared__ __align__(16) signed char ldsx[64 * 272];
    const int tid  = threadIdx.x;
    const int lane = tid & 63;
    const int wv   = tid >> 6;
    const int obase = wv * 32;
    const int lr = lane & 15, quad = lane >> 4;
    const size_t rb0 = (size_t)blockIdx.x * 64;

    v4f f[8];
    const v4f* xb = (const v4f*)(x + rb0 * 256);
    #pragma unroll
    for (int j = 0; j < 8; ++j)
        f[j] = xb[j * 512 + tid];

    v4i wf[2][4];
    #pragma unroll
    for (int ot = 0; ot < 2; ++ot)
        #pragma unroll
        for (int kt = 0; kt < 4; ++kt)
            wf[ot][kt] = *(const v4i*)(wq + (size_t)(obase + ot * 16 + lr) * 256 + kt * 64 + quad * 16);

    #pragma unroll
    for (int j = 0; j < 8; ++j) {
        int idx = j * 512 + tid;
        int row = idx >> 6, c = idx & 63;
        int b0 = (int)rintf(fminf(fmaxf(f[j][0], 0.f), 1.f) * 15.f);
        int b1 = (int)rintf(fminf(fmaxf(f[j][1], 0.f), 1.f) * 15.f);
        int b2 = (int)rintf(fminf(fmaxf(f[j][2], 0.f), 1.f) * 15.f);
        int b3 = (int)rintf(fminf(fmaxf(f[j][3], 0.f), 1.f) * 15.f);
        *(int*)(ldsx + row * 272 + c * 4) = b0 | (b1 << 8) | (b2 << 16) | (b3 << 24);
    }
    __syncthreads();

    int ssum[2] = {0, 0};
    int ssq[2]  = {0, 0};

    #pragma unroll
    for (int t = 0; t < 4; ++t) {
        v4i a[4];
        #pragma unroll
        for (int kt = 0; kt < 4; ++kt)
            a[kt] = *(const v4i*)(ldsx + (t * 16 + lr) * 272 + kt * 64 + quad * 16);
        #pragma unroll
        for (int ot = 0; ot < 2; ++ot) {
            v4i acc0 = {0, 0, 0, 0}, acc1 = {0, 0, 0, 0};
            acc0 = __builtin_amdgcn_mfma_i32_16x16x64_i8(a[0], wf[ot][0], acc0, 0, 0, 0);
            acc0 = __builtin_amdgcn_mfma_i32_16x16x64_i8(a[1], wf[ot][1], acc0, 0, 0, 0);
            acc1 = __builtin_amdgcn_mfma_i32_16x16x64_i8(a[2], wf[ot][2], acc1, 0, 0, 0);
            acc1 = __builtin_amdgcn_mfma_i32_16x16x64_i8(a[3], wf[ot][3], acc1, 0, 0, 0);
            const int ocol = obase + ot * 16 + lr;
            if constexpr (sizeof(ST) == 1) {
                unsigned pack = 0;
                #pragma unroll
                for (int e = 0; e < 4; ++e) {
                    int s = rhe1792(acc0[e]) + rhe1792(acc1[e]);
                    ssum[ot] += s;
                    ssq[ot]  += s * s;
                    pack |= (unsigned)(s & 255) << (8 * e);
                }
                const size_t rg = (size_t)blockIdx.x * 16 + t * 4 + quad;
                ((unsigned*)sbuf)[rg * 256 + ocol] = pack;
            } else {
                ST* sp = sbuf + (rb0 + (size_t)t * 16 + quad * 4) * 256 + ocol;
                #pragma unroll
                for (int e = 0; e < 4; ++e) {
                    int s = rhe1792(acc0[e]) + rhe1792(acc1[e]);
                    ssum[ot] += s;
                    ssq[ot]  += s * s;
                    sp[(size_t)e * 256] = (ST)s;
                }
            }
        }
    }
    int* st = stats + (blockIdx.x & (NREP - 1)) * 512;
    #pragma unroll
    for (int ot = 0; ot < 2; ++ot) {
        int v = ssum[ot], u = ssq[ot];
        v += __shfl_xor(v, 16, 64); v += __shfl_xor(v, 32, 64);
        u += __shfl_xor(u, 16, 64); u += __shfl_xor(u, 32, 64);
        if (quad == 0) {
            atomicAdd(&st[obase + ot * 16 + lr], v);
            atomicAdd(&st[256 + obase + ot * 16 + lr], u);
        }
    }
}

template <typename LT>
__global__ __launch_bounds__(256) void k_out(const LT* sbuf, const int* __restrict__ stats,
                                             const float* __restrict__ partials,
                                             const float* __restrict__ gamma,
                                             const float* __restrict__ beta,
                                             float* out)
{
    __shared__ float2 ab[256];
    const int tid = threadIdx.x;
    {
        int o = tid;
        int s = 0, q = 0;
        #pragma unroll
        for (int rr = 0; rr < NREP; ++rr) {
            s += stats[rr * 512 + o];
            q += stats[rr * 512 + 256 + o];
        }
        float scale_w = reduce_partials(partials, o) / 7.0f;
        float t = scale_w / 15.0f;
        double Cs = 1792.0 * (double)t;
        const double N = 65536.0;
        double mean_s = (double)s / N;
        double var_s  = (double)q / N - mean_s * mean_s;
        double var    = Cs * Cs * var_s;
        double inv    = 1.0 / sqrt(var + 1e-5);
        double A = Cs * inv * (double)gamma[o];
        double B = (double)beta[o] - Cs * mean_s * inv * (double)gamma[o];
        ab[o] = make_float2((float)A, (float)B);
    }
    __syncthreads();

    const int b = blockIdx.x;
    const int d = ((b & 7) << 2) | ((b >> 3) & 3) | (b & ~31);
    const int ci = tid & 63;
    const int c0 = ci * 4;
    const float2 p0 = ab[c0], p1 = ab[c0 + 1], p2 = ab[c0 + 2], p3 = ab[c0 + 3];
    const float inv15 = 0.066666666666666666f;

    if constexpr (sizeof(LT) == 1) {
        const int rg = d * 4 + (tid >> 6);
        v4i V = ((const v4i*)sbuf)[(size_t)rg * 64 + ci];
        #pragma unroll
        for (int j = 0; j < 4; ++j) {
            float v0 = (float)((V[0] << (24 - 8 * j)) >> 24);
            float v1 = (float)((V[1] << (24 - 8 * j)) >> 24);
            float v2 = (float)((V[2] << (24 - 8 * j)) >> 24);
            float v3 = (float)((V[3] << (24 - 8 * j)) >> 24);
            float y0 = rintf(fminf(fmaxf(v0 * p0.x + p0.y, 0.f), 1.f) * 15.f);
            float y1 = rintf(fminf(fmaxf(v1 * p1.x + p1.y, 0.f), 1.f) * 15.f);
            float y2 = rintf(fminf(fmaxf(v2 * p2.x + p2.y, 0.f), 1.f) * 15.f);
            float y3 = rintf(fminf(fmaxf(v3 * p3.x + p3.y, 0.f), 1.f) * 15.f);
            v4f o = { y0 * inv15, y1 * inv15, y2 * inv15, y3 * inv15 };
            __builtin_nontemporal_store(o, (v4f*)out + (size_t)(4 * rg + j) * 64 + ci);
        }
    } else {
        const size_t base = (size_t)d * 1024 + tid;
        #pragma unroll
        for (int j = 0; j < 4; ++j) {
            const size_t F4 = base + (size_t)j * 256;
            v4f fl = ((const v4f*)sbuf)[F4];
            const int oo = (tid * 4) & 255;
            float2 q0 = ab[oo], q1 = ab[oo + 1], q2 = ab[oo + 2], q3 = ab[oo + 3];
            float y0 = rintf(fminf(fmaxf(fl[0] * q0.x + q0.y, 0.f), 1.f) * 15.f);
            float y1 = rintf(fminf(fmaxf(fl[1] * q1.x + q1.y, 0.f), 1.f) * 15.f);
            float y2 = rintf(fminf(fmaxf(fl[2] * q2.x + q2.y, 0.f), 1.f) * 15.f);
            float y3 = rintf(fminf(fmaxf(fl[3] * q3.x + q3.y, 0.f), 1.f) * 15.f);
            v4f o = { y0 * inv15, y1 * inv15, y2 * inv15, y3 * inv15 };
            __builtin_nontemporal_store(o, (v4f*)out + F4);
        }
    }
}

// ---------------- launch ----------------
extern "C" void kernel_launch(void* const* d_in, const int* in_sizes, int n_in,
                              void* d_out, int out_size, void* d_ws, size_t ws_size,
                              hipStream_t stream)
{
    const float* x     = (const float*)d_in[0];
    const float* w     = (const float*)d_in[1];
    const float* gamma = (const float*)d_in[2];
    const float* beta  = (const float*)d_in[3];
    float* out = (float*)d_out;
    char* ws = (char*)d_ws;

    signed char* wq       = (signed char*)(ws + WQ_OFF);
    int*         stats    = (int*)(ws + STATS_OFF);
    float*       partials = (float*)(ws + PART_OFF);
    int*         bar      = (int*)(ws + BAR_OFF);

    k_maxabs<<<dim3(64), dim3(256), 0, stream>>>(w, partials, stats, bar);
    k_wquant<<<dim3(64), dim3(256), 0, stream>>>(w, partials, wq);

    if (ws_size >= WS_MIN) {
        k_fused<<<dim3(256), dim3(512), 0, stream>>>(x, wq, partials, stats, bar,
                                                     gamma, beta, out);
    } else {
        // fallback: old proven 4-kernel pipeline
        if (ws_size >= WS_SBUF_NEEDED) {
            signed char* sbuf = (signed char*)(ws + SBUF_OFF);
            k_gemm<signed char><<<dim3(1024), dim3(512), 0, stream>>>(x, wq, sbuf, stats);
            k_out<signed char><<<dim3(4096), dim3(256), 0, stream>>>(sbuf, stats, partials,
                                                                     gamma, beta, out);
        } else {
            k_gemm<float><<<dim3(1024), dim3(512), 0, stream>>>(x, wq, out, stats);
            k_out<float><<<dim3(4096), dim3(256), 0, stream>>>(out, stats, partials,
                                                               gamma, beta, out);
        }
    }
}